// Round 11
// baseline (186.855 us; speedup 1.0000x reference)
//
#include <hip/hip_runtime.h>

typedef unsigned short u16;
typedef unsigned int u32;
typedef __attribute__((ext_vector_type(8))) short short8;
typedef __attribute__((ext_vector_type(4))) float f32x4;

__device__ __forceinline__ u16 f2bf(float f) {
  union { float f; u32 u; } c; c.f = f;
  u32 u = c.u;
  u += 0x7fffu + ((u >> 16) & 1u);  // round-to-nearest-even
  return (u16)(u >> 16);
}
__device__ __forceinline__ float bf2f(u16 h) {
  union { u32 u; float f; } c; c.u = ((u32)h) << 16;
  return c.f;
}

// async global->LDS, 16B per lane; LDS dest must be linear in lane order
#define GLDS16(g, l)                                                          \
  __builtin_amdgcn_global_load_lds(                                           \
      (const __attribute__((address_space(1))) u32*)(g),                      \
      (__attribute__((address_space(3))) u32*)(l), 16, 0, 0)

// exp(x*0.125) == exp2(x * 0.125*log2(e))
#define EXP_SCALE 0.18033688011112042f

// ---------------------------------------------------------------- cast x
__global__ __launch_bounds__(256) void k_cast_x(const float* __restrict__ x,
                                                u16* __restrict__ xb) {
  int i = blockIdx.x * 256 + threadIdx.x;
  float4 v = ((const float4*)x)[i];
  short4 s;
  s.x = (short)f2bf(v.x); s.y = (short)f2bf(v.y);
  s.z = (short)f2bf(v.z); s.w = (short)f2bf(v.w);
  *(short4*)(xb + (size_t)i * 4) = s;
}

// ------------------------------------------- transpose + cast weights (D=1024)
__global__ __launch_bounds__(256) void k_trans_w(
    const float* __restrict__ W0, const float* __restrict__ W1,
    const float* __restrict__ W2, const float* __restrict__ W3,
    u16* __restrict__ T0, u16* __restrict__ T1, u16* __restrict__ T2,
    u16* __restrict__ T3) {
  const float* W = blockIdx.z == 0 ? W0 : blockIdx.z == 1 ? W1 : blockIdx.z == 2 ? W2 : W3;
  u16* T = blockIdx.z == 0 ? T0 : blockIdx.z == 1 ? T1 : blockIdx.z == 2 ? T2 : T3;
  __shared__ float tile[32][33];
  int r0 = blockIdx.y * 32, c0 = blockIdx.x * 32;
  int tid = threadIdx.x;
  for (int i = tid; i < 1024; i += 256) {
    int r = i >> 5, c = i & 31;
    tile[r][c] = W[(size_t)(r0 + r) * 1024 + c0 + c];
  }
  __syncthreads();
  for (int i = tid; i < 1024; i += 256) {
    int r = i >> 5, c = i & 31;
    T[(size_t)(c0 + r) * 1024 + r0 + c] = f2bf(tile[c][r]);
  }
}

// -------------------- k_proj: 256x256 tile, BK=32, 3-slot counted rotation
// R11: k_proj is L3-BW-bound on staging traffic (R8: 402MB/63.8us = 6.3TB/s).
// 256^2 tiles halve staged bytes to ~192MB; the 3-slot rotation (proven
// race-safe in R7/R8: lgkmcnt(0) drained WITH vmcnt before every barrier,
// counted vmcnt keeps 2 stages in flight) keeps demand continuous, unlike
// R10's per-tile drain which only reached 2.2TB/s. Per-XCD remap groups
// (which, n-panel) so the <=1MB B-set is L2-resident; A streams from L3.
__global__ __launch_bounds__(512, 2) void k_proj(
    const u16* __restrict__ xb, const u16* __restrict__ WqT,
    const u16* __restrict__ WkT, const u16* __restrict__ WvT,
    const float* __restrict__ bq, const float* __restrict__ bk,
    const float* __restrict__ bv, u16* __restrict__ qh, u16* __restrict__ kh,
    u16* __restrict__ vh, u16* __restrict__ vT) {
  __shared__ __align__(16) u16 As[3 * 256 * 32];   // 48KB
  __shared__ __align__(16) u16 Bs[3 * 256 * 32];   // 48KB
  // remap: per-XCD (li&7) blocks share (which, n) -> B-panels L2-resident
  const int li = blockIdx.x;
  const int cx = li & 7, j = li >> 3;       // j in [0,24)
  const int g = cx * 24 + j;                // [0,192)
  const int which = g >> 6;                 // 64 blocks per which
  const int rem = g & 63;
  const int n0 = (rem >> 4) * 256;          // 4 n-panels
  const int m0 = (rem & 15) * 256;          // 16 m-panels
  const u16* Ag = xb + (size_t)m0 * 1024;
  const u16* Bg = (which == 0 ? WqT : which == 1 ? WkT : WvT) + (size_t)n0 * 1024;
  const float* bias = which == 0 ? bq : which == 1 ? bk : bv;
  const int tid = threadIdx.x, lane = tid & 63, wid = tid >> 6;
  const int wm = wid >> 2, wn = wid & 3, fr = lane & 15, fg = lane >> 4;

  f32x4 acc[8][4];
#pragma unroll
  for (int i = 0; i < 8; ++i)
#pragma unroll
    for (int jj = 0; jj < 4; ++jj) acc[i][jj] = f32x4{0.f, 0.f, 0.f, 0.f};

  auto stage = [&](int t, int slot) {
    u16* as = As + slot * 8192;
    u16* bs = Bs + slot * 8192;
#pragma unroll
    for (int L = 0; L < 2; ++L) {
      int q = L * 512 + tid;               // 0..1023 chunk id (row,c)
      int row = q >> 2, c = q & 3;
      GLDS16(Ag + (size_t)row * 1024 + t * 32 + c * 8, as + q * 8);
    }
#pragma unroll
    for (int L = 0; L < 2; ++L) {
      int q = L * 512 + tid;
      int row = q >> 2, c = q & 3;
      GLDS16(Bg + (size_t)row * 1024 + t * 32 + c * 8, bs + q * 8);
    }
  };
  auto compute = [&](int slot) {
    const u16* as = As + slot * 8192;
    const u16* bs = Bs + slot * 8192;
    short8 bf_[4];
#pragma unroll
    for (int jj = 0; jj < 4; ++jj) {
      int row = wn * 64 + jj * 16 + fr;
      bf_[jj] = *(const short8*)(bs + row * 32 + fg * 8);
    }
    short8 af_[8];
#pragma unroll
    for (int i = 0; i < 8; ++i) {
      int row = wm * 128 + i * 16 + fr;
      af_[i] = *(const short8*)(as + row * 32 + fg * 8);
    }
#pragma unroll
    for (int i = 0; i < 8; ++i)
#pragma unroll
      for (int jj = 0; jj < 4; ++jj)
        acc[i][jj] = __builtin_amdgcn_mfma_f32_16x16x32_bf16(af_[i], bf_[jj],
                                                             acc[i][jj], 0, 0, 0);
  };

  const int NS = 32;  // K=1024 / BK=32
  stage(0, 0);
  stage(1, 1);
  int cs = 0, ss = 2;
  for (int t = 0; t + 2 < NS; ++t) {
    asm volatile("s_waitcnt vmcnt(4) lgkmcnt(0)" ::: "memory");
    __builtin_amdgcn_s_barrier();
    asm volatile("" ::: "memory");
    stage(t + 2, ss);
    compute(cs);
    cs = cs == 2 ? 0 : cs + 1;
    ss = ss == 2 ? 0 : ss + 1;
  }
  asm volatile("s_waitcnt vmcnt(4) lgkmcnt(0)" ::: "memory");
  __builtin_amdgcn_s_barrier();
  asm volatile("" ::: "memory");
  compute(cs);
  cs = cs == 2 ? 0 : cs + 1;
  asm volatile("s_waitcnt vmcnt(0) lgkmcnt(0)" ::: "memory");
  __builtin_amdgcn_s_barrier();
  asm volatile("" ::: "memory");
  compute(cs);

  // ---- epilogue ----
#pragma unroll
  for (int f = 0; f < 8; ++f)
#pragma unroll
    for (int j2 = 0; j2 < 4; ++j2) {
      int n = n0 + wn * 64 + j2 * 16 + fr;
      float bb = bias[n];
      int h = n >> 6, dc = n & 63;
#pragma unroll
      for (int r = 0; r < 4; ++r) {
        int m = m0 + wm * 128 + f * 16 + fg * 4 + r;
        int b = m >> 10, nr = m & 1023;
        int z = b * 16 + h;
        float val = acc[f][j2][r] + bb;
        u16 bv16 = f2bf(val);
        if (which == 0) {
          qh[((size_t)z * 1024 + nr) * 64 + dc] = bv16;
        } else if (which == 1) {
          kh[((size_t)z * 1024 + nr) * 64 + dc] = bv16;
        } else {
          vh[((size_t)z * 1024 + nr) * 64 + dc] = bv16;
          vT[((size_t)z * 64 + dc) * 1024 + nr] = bv16;
        }
      }
    }
}

// 3-slot pipelined core for k_final (proven config, unchanged)
__device__ __forceinline__ void core128x64_p3(const u16* __restrict__ A,
                                              const u16* __restrict__ Bt, int K,
                                              f32x4 (&acc)[2][4], u16* As,
                                              u16* Bs) {
  const int tid = threadIdx.x;
  const int lane = tid & 63;
  const int w = tid >> 6;
  const int fr = lane & 15, fg = lane >> 4;
  const int sr = tid >> 2, sc = (tid & 3) * 8;
#pragma unroll
  for (int i = 0; i < 2; ++i)
#pragma unroll
    for (int j = 0; j < 4; ++j) acc[i][j] = f32x4{0.f, 0.f, 0.f, 0.f};

  auto stage = [&](int t, int slot) {
    u16* as = As + slot * 4096;
    u16* bs = Bs + slot * 2048;
    const int k0 = t * 32 + sc;
    GLDS16(A + (size_t)sr * K + k0, as + tid * 8);
    GLDS16(A + (size_t)(sr + 64) * K + k0, as + (256 + tid) * 8);
    GLDS16(Bt + (size_t)sr * K + k0, bs + tid * 8);
  };
  auto compute = [&](int slot) {
    const u16* as = As + slot * 4096;
    const u16* bs = Bs + slot * 2048;
    short8 af[2], bfv[4];
#pragma unroll
    for (int i = 0; i < 2; ++i)
      af[i] = *(const short8*)(as + (w * 32 + i * 16 + fr) * 32 + fg * 8);
#pragma unroll
    for (int j = 0; j < 4; ++j)
      bfv[j] = *(const short8*)(bs + (j * 16 + fr) * 32 + fg * 8);
#pragma unroll
    for (int i = 0; i < 2; ++i)
#pragma unroll
      for (int j = 0; j < 4; ++j)
        acc[i][j] = __builtin_amdgcn_mfma_f32_16x16x32_bf16(af[i], bfv[j],
                                                            acc[i][j], 0, 0, 0);
  };

  const int NS = K / 32;
  stage(0, 0);
  stage(1, 1);
  int cs = 0, ss = 2;
  for (int t = 0; t + 2 < NS; ++t) {
    asm volatile("s_waitcnt vmcnt(3) lgkmcnt(0)" ::: "memory");
    __builtin_amdgcn_s_barrier();
    asm volatile("" ::: "memory");
    stage(t + 2, ss);
    compute(cs);
    cs = cs == 2 ? 0 : cs + 1;
    ss = ss == 2 ? 0 : ss + 1;
  }
  asm volatile("s_waitcnt vmcnt(3) lgkmcnt(0)" ::: "memory");
  __builtin_amdgcn_s_barrier();
  asm volatile("" ::: "memory");
  compute(cs);
  cs = cs == 2 ? 0 : cs + 1;
  asm volatile("s_waitcnt vmcnt(0) lgkmcnt(0)" ::: "memory");
  __builtin_amdgcn_s_barrier();
  asm volatile("" ::: "memory");
  compute(cs);
}

// -------------------------------------------------------------- pass 1
__global__ __launch_bounds__(256) void k_pass1(
    const u16* __restrict__ qh, const u16* __restrict__ kh,
    const u16* __restrict__ vT, u16* __restrict__ P1T,
    u16* __restrict__ P1h, float* __restrict__ mlinv) {
  __shared__ __align__(16) u16 Ks[64 * 64];
  __shared__ __align__(16) u16 Vs[64 * 64];
  __shared__ __align__(16) u16 Ps[4][16 * 64];
  const int li = blockIdx.x + 16 * blockIdx.y;
  const int cx = li & 7, jb = li >> 3;
  const int z = cx * 8 + (jb >> 4);
  const int m0 = (jb & 15) * 64;
  const int tid = threadIdx.x, lane = tid & 63, w = tid >> 6;
  const int fr = lane & 15, fg = lane >> 4;
  const int row0 = m0 + w * 16;
  const u16* qbase = qh + (size_t)z * 65536;
  const u16* kbase = kh + (size_t)z * 65536;
  const u16* vbase = vT + (size_t)z * 65536;
  u16* myP = &Ps[w][0];

  short8 qf[2];
#pragma unroll
  for (int kc = 0; kc < 2; ++kc)
    qf[kc] = *(const short8*)(qbase + (size_t)(row0 + fr) * 64 + (kc * 4 + fg) * 8);

  f32x4 o[4];
  float rs[4];
#pragma unroll
  for (int ct = 0; ct < 4; ++ct) o[ct] = f32x4{0.f, 0.f, 0.f, 0.f};
#pragma unroll
  for (int r = 0; r < 4; ++r) rs[r] = 0.f;

  for (int t = 0; t < 16; ++t) {
    const int kv0 = t * 64;
#pragma unroll
    for (int it = 0; it < 2; ++it) {
      int idx = it * 256 + tid;
      int row = idx >> 3, cc = idx & 7;
      GLDS16(kbase + (size_t)(kv0 + row) * 64 + ((cc ^ (row & 7)) * 8),
             Ks + idx * 8);
      GLDS16(vbase + (size_t)row * 1024 + kv0 + ((cc ^ (row & 7)) * 8),
             Vs + idx * 8);
    }
    __syncthreads();
#pragma unroll
    for (int ct = 0; ct < 4; ++ct) {
      int krow = ct * 16 + fr;
      short8 k0 = *(const short8*)(Ks + krow * 64 + ((fg ^ (krow & 7)) * 8));
      short8 k1 = *(const short8*)(Ks + krow * 64 + (((4 + fg) ^ (krow & 7)) * 8));
      f32x4 s = __builtin_amdgcn_mfma_f32_16x16x32_bf16(
          qf[0], k0, f32x4{0.f, 0.f, 0.f, 0.f}, 0, 0, 0);
      s = __builtin_amdgcn_mfma_f32_16x16x32_bf16(qf[1], k1, s, 0, 0, 0);
      int pcol = ct * 16 + fr;
      int cc = pcol >> 3;
#pragma unroll
      for (int r = 0; r < 4; ++r) {
        float e = __builtin_exp2f(s[r] * EXP_SCALE);
        rs[r] += e;
        int prow = fg * 4 + r;
        myP[prow * 64 + ((cc ^ (prow & 7)) * 8) + (pcol & 7)] = f2bf(e);
      }
    }
    asm volatile("s_waitcnt lgkmcnt(0)" ::: "memory");
    short8 p0 = *(const short8*)(myP + fr * 64 + ((fg ^ (fr & 7)) * 8));
    short8 p1 = *(const short8*)(myP + fr * 64 + (((4 + fg) ^ (fr & 7)) * 8));
#pragma unroll
    for (int ct = 0; ct < 4; ++ct) {
      int vrow = ct * 16 + fr;
      short8 v0 = *(const short8*)(Vs + vrow * 64 + ((fg ^ (vrow & 7)) * 8));
      short8 v1 = *(const short8*)(Vs + vrow * 64 + (((4 + fg) ^ (vrow & 7)) * 8));
      o[ct] = __builtin_amdgcn_mfma_f32_16x16x32_bf16(p0, v0, o[ct], 0, 0, 0);
      o[ct] = __builtin_amdgcn_mfma_f32_16x16x32_bf16(p1, v1, o[ct], 0, 0, 0);
    }
    __syncthreads();
  }
#pragma unroll
  for (int off = 1; off < 16; off <<= 1)
#pragma unroll
    for (int r = 0; r < 4; ++r) rs[r] += __shfl_xor(rs[r], off, 64);
  float linv[4];
#pragma unroll
  for (int r = 0; r < 4; ++r) linv[r] = 1.f / rs[r];
#pragma unroll
  for (int ct = 0; ct < 4; ++ct) {
    union { u16 u[4]; short4 s4; } pk;
#pragma unroll
    for (int r = 0; r < 4; ++r) {
      u16 b_ = f2bf(o[ct][r] * linv[r]);
      pk.u[r] = b_;
      myP[(fg * 4 + r) * 64 + ct * 16 + fr] = b_;  // linear stage
    }
    *(short4*)(P1T + ((size_t)z * 64 + ct * 16 + fr) * 1024 + row0 + fg * 4) =
        pk.s4;
  }
  asm volatile("s_waitcnt lgkmcnt(0)" ::: "memory");
  {
    int r_ = lane >> 2;
#pragma unroll
    for (int ch2 = 0; ch2 < 2; ++ch2) {
      int ch = (lane & 3) * 2 + ch2;
      int4 vv = *(const int4*)(myP + r_ * 64 + ch * 8);
      *(int4*)(P1h + ((size_t)z * 1024 + row0 + r_) * 64 + ch * 8) = vv;
    }
  }
  if (fr == 0) {
#pragma unroll
    for (int r = 0; r < 4; ++r)
      mlinv[(size_t)z * 1024 + row0 + fg * 4 + r] = linv[r];
  }
}

// -------------------------------------------------------------- pass 2
__global__ __launch_bounds__(256) void k_pass2(
    const u16* __restrict__ qh, const u16* __restrict__ kh,
    const u16* __restrict__ P1T, const u16* __restrict__ vh,
    const u16* __restrict__ P1h, const float* __restrict__ mlinv,
    const float* __restrict__ w0, const float* __restrict__ w1,
    const float* __restrict__ wK, u16* __restrict__ OH) {
  __shared__ __align__(16) u16 Ks[64 * 64];
  __shared__ __align__(16) u16 Ts[64 * 64];
  __shared__ __align__(16) u16 Ps[4][16 * 64];
  const int li = blockIdx.x + 16 * blockIdx.y;
  const int cx = li & 7, jb = li >> 3;
  const int z = cx * 8 + (jb >> 4);
  const int m0 = (jb & 15) * 64;
  const int tid = threadIdx.x, lane = tid & 63, w = tid >> 6;
  const int fr = lane & 15, fg = lane >> 4;
  const int row0 = m0 + w * 16;
  const int h = z & 15, b = z >> 4;
  const float cw0 = w0[h], cw1 = w1[h] - wK[h], cw2 = 2.f * wK[h];
  const u16* qbase = qh + (size_t)z * 65536;
  const u16* kbase = kh + (size_t)z * 65536;
  const u16* tbase = P1T + (size_t)z * 65536;
  u16* myP = &Ps[w][0];

  short8 qf[2];
#pragma unroll
  for (int kc = 0; kc < 2; ++kc)
    qf[kc] = *(const short8*)(qbase + (size_t)(row0 + fr) * 64 + (kc * 4 + fg) * 8);
  float lrow[4];
#pragma unroll
  for (int r = 0; r < 4; ++r)
    lrow[r] = mlinv[(size_t)z * 1024 + row0 + fg * 4 + r];
  f32x4 o[4];
#pragma unroll
  for (int ct = 0; ct < 4; ++ct) o[ct] = f32x4{0.f, 0.f, 0.f, 0.f};

  for (int t = 0; t < 16; ++t) {
    const int kv0 = t * 64;
#pragma unroll
    for (int it = 0; it < 2; ++it) {
      int idx = it * 256 + tid;
      int row = idx >> 3, cc = idx & 7;
      GLDS16(kbase + (size_t)(kv0 + row) * 64 + ((cc ^ (row & 7)) * 8),
             Ks + idx * 8);
      GLDS16(tbase + (size_t)row * 1024 + kv0 + ((cc ^ (row & 7)) * 8),
             Ts + idx * 8);
    }
    __syncthreads();
#pragma unroll
    for (int ct = 0; ct < 4; ++ct) {
      int krow = ct * 16 + fr;
      short8 k0 = *(const short8*)(Ks + krow * 64 + ((fg ^ (krow & 7)) * 8));
      short8 k1 = *(const short8*)(Ks + krow * 64 + (((4 + fg) ^ (krow & 7)) * 8));
      f32x4 s = __builtin_amdgcn_mfma_f32_16x16x32_bf16(
          qf[0], k0, f32x4{0.f, 0.f, 0.f, 0.f}, 0, 0, 0);
      s = __builtin_amdgcn_mfma_f32_16x16x32_bf16(qf[1], k1, s, 0, 0, 0);
      int pcol = ct * 16 + fr;
      int cc = pcol >> 3;
#pragma unroll
      for (int r = 0; r < 4; ++r) {
        float p = __builtin_exp2f(s[r] * EXP_SCALE) * lrow[r];
        int prow = fg * 4 + r;
        myP[prow * 64 + ((cc ^ (prow & 7)) * 8) + (pcol & 7)] = f2bf(p);
      }
    }
    asm volatile("s_waitcnt lgkmcnt(0)" ::: "memory");
    short8 p0 = *(const short8*)(myP + fr * 64 + ((fg ^ (fr & 7)) * 8));
    short8 p1 = *(const short8*)(myP + fr * 64 + (((4 + fg) ^ (fr & 7)) * 8));
#pragma unroll
    for (int ct = 0; ct < 4; ++ct) {
      int vrow = ct * 16 + fr;
      short8 v0 = *(const short8*)(Ts + vrow * 64 + ((fg ^ (vrow & 7)) * 8));
      short8 v1 = *(const short8*)(Ts + vrow * 64 + (((4 + fg) ^ (vrow & 7)) * 8));
      o[ct] = __builtin_amdgcn_mfma_f32_16x16x32_bf16(p0, v0, o[ct], 0, 0, 0);
      o[ct] = __builtin_amdgcn_mfma_f32_16x16x32_bf16(p1, v1, o[ct], 0, 0, 0);
    }
    __syncthreads();
  }
#pragma unroll
  for (int ct = 0; ct < 4; ++ct)
#pragma unroll
    for (int r = 0; r < 4; ++r)
      myP[(fg * 4 + r) * 64 + ct * 16 + fr] = f2bf(o[ct][r]);
  asm volatile("s_waitcnt lgkmcnt(0)" ::: "memory");
  {
    int r_ = lane >> 2;
    const u16* vp = vh + ((size_t)z * 1024 + row0 + r_) * 64;
    const u16* pp = P1h + ((size_t)z * 1024 + row0 + r_) * 64;
    u16* op = OH + ((size_t)b * 1024 + row0 + r_) * 1024 + h * 64;
#pragma unroll
    for (int ch2 = 0; ch2 < 2; ++ch2) {
      int ch = (lane & 3) * 2 + ch2;
      short8 pv = *(const short8*)(myP + r_ * 64 + ch * 8);
      short8 vv = *(const short8*)(vp + ch * 8);
      short8 p1 = *(const short8*)(pp + ch * 8);
      short8 res;
#pragma unroll
      for (int e = 0; e < 8; ++e) {
        float f = cw0 * bf2f((u16)vv[e]) + cw1 * bf2f((u16)p1[e]) +
                  cw2 * bf2f((u16)pv[e]);
        res[e] = (short)f2bf(f);
      }
      *(short8*)(op + ch * 8) = res;
    }
  }
}

// ------------------------------------------------- final: out = OH @ Wo + bo
__global__ __launch_bounds__(256) void k_final(const u16* __restrict__ OH,
                                               const u16* __restrict__ WoT,
                                               const float* __restrict__ bo,
                                               float* __restrict__ out) {
  __shared__ __align__(16) u16 As[3 * 128 * 32];
  __shared__ __align__(16) u16 Bs[3 * 64 * 32];
  const int li = blockIdx.x + 32 * blockIdx.y;
  const int cx = li & 7, jb = li >> 3;
  const int m0 = (cx * 4 + (jb & 3)) * 128;
  const int n0 = (jb >> 2) * 64;
  f32x4 acc[2][4];
  core128x64_p3(OH + (size_t)m0 * 1024, WoT + (size_t)n0 * 1024, 1024, acc, As, Bs);
  const int tid = threadIdx.x, lane = tid & 63, w = tid >> 6;
  const int fr = lane & 15, fg = lane >> 4;
#pragma unroll
  for (int i = 0; i < 2; ++i)
#pragma unroll
    for (int j2 = 0; j2 < 4; ++j2) {
      int n = n0 + j2 * 16 + fr;
      float bb = bo[n];
#pragma unroll
      for (int r = 0; r < 4; ++r) {
        int m = m0 + w * 32 + i * 16 + fg * 4 + r;
        out[(size_t)m * 1024 + n] = acc[i][j2][r] + bb;
      }
    }
}

extern "C" void kernel_launch(void* const* d_in, const int* in_sizes, int n_in,
                              void* d_out, int out_size, void* d_ws,
                              size_t ws_size, hipStream_t stream) {
  const float* x = (const float*)d_in[0];
  const float* Wq = (const float*)d_in[1];
  const float* bq = (const float*)d_in[2];
  const float* Wk = (const float*)d_in[3];
  const float* bk = (const float*)d_in[4];
  const float* Wv = (const float*)d_in[5];
  const float* bv = (const float*)d_in[6];
  const float* Wo = (const float*)d_in[7];
  const float* bo = (const float*)d_in[8];
  const float* w0 = (const float*)d_in[9];
  const float* w1 = (const float*)d_in[10];
  const float* wK = (const float*)d_in[11];
  float* out = (float*)d_out;

  char* ws = (char*)d_ws;
  const size_t MB = 1ull << 20;
  u16* xb  = (u16*)(ws);             // 8 MiB
  u16* WqT = (u16*)(ws + 8 * MB);    // 2 MiB
  u16* WkT = (u16*)(ws + 10 * MB);   // 2 MiB
  u16* WvT = (u16*)(ws + 12 * MB);   // 2 MiB
  u16* WoT = (u16*)(ws + 14 * MB);   // 2 MiB
  u16* qh  = (u16*)(ws + 16 * MB);   // 8 MiB  [z][n][d]
  u16* kh  = (u16*)(ws + 24 * MB);   // 8 MiB  [z][n][d]
  u16* vh  = (u16*)(ws + 32 * MB);   // 8 MiB  [z][n][d]
  u16* vT  = (u16*)(ws + 40 * MB);   // 8 MiB  [z][d][n]
  u16* P1T = (u16*)(ws + 48 * MB);   // 8 MiB  [z][d][n]
  u16* P1h = (u16*)(ws + 56 * MB);   // 8 MiB  [z][n][d]
  u16* OH  = (u16*)(ws + 64 * MB);   // 8 MiB  [b][n][D]
  float* mlinv = (float*)(ws + 72 * MB);  // 256 KiB [z][n]

  hipLaunchKernelGGL(k_cast_x, dim3(4096), dim3(256), 0, stream, x, xb);
  hipLaunchKernelGGL(k_trans_w, dim3(32, 32, 4), dim3(256), 0, stream, Wq, Wk,
                     Wv, Wo, WqT, WkT, WvT, WoT);
  hipLaunchKernelGGL(k_proj, dim3(192), dim3(512), 0, stream, xb, WqT, WkT,
                     WvT, bq, bk, bv, qh, kh, vh, vT);
  hipLaunchKernelGGL(k_pass1, dim3(16, 64), dim3(256), 0, stream, qh, kh, vT,
                     P1T, P1h, mlinv);
  hipLaunchKernelGGL(k_pass2, dim3(16, 64), dim3(256), 0, stream, qh, kh, P1T,
                     vh, P1h, mlinv, w0, w1, wK, OH);
  hipLaunchKernelGGL(k_final, dim3(32, 16), dim3(256), 0, stream, OH, WoT, bo,
                     out);
}

// Round 12
// 186.694 us; speedup vs baseline: 1.0009x; 1.0009x over previous
//
#include <hip/hip_runtime.h>

typedef unsigned short u16;
typedef unsigned int u32;
typedef __attribute__((ext_vector_type(8))) short short8;
typedef __attribute__((ext_vector_type(4))) float f32x4;

__device__ __forceinline__ u16 f2bf(float f) {
  union { float f; u32 u; } c; c.f = f;
  u32 u = c.u;
  u += 0x7fffu + ((u >> 16) & 1u);  // round-to-nearest-even
  return (u16)(u >> 16);
}
__device__ __forceinline__ float bf2f(u16 h) {
  union { u32 u; float f; } c; c.u = ((u32)h) << 16;
  return c.f;
}

// async global->LDS, 16B per lane; LDS dest must be linear in lane order
#define GLDS16(g, l)                                                          \
  __builtin_amdgcn_global_load_lds(                                           \
      (const __attribute__((address_space(1))) u32*)(g),                      \
      (__attribute__((address_space(3))) u32*)(l), 16, 0, 0)

// exp(x*0.125) == exp2(x * 0.125*log2(e))
#define EXP_SCALE 0.18033688011112042f

// ---------------------------------------------------------------- cast x
__global__ __launch_bounds__(256) void k_cast_x(const float* __restrict__ x,
                                                u16* __restrict__ xb) {
  int i = blockIdx.x * 256 + threadIdx.x;
  float4 v = ((const float4*)x)[i];
  short4 s;
  s.x = (short)f2bf(v.x); s.y = (short)f2bf(v.y);
  s.z = (short)f2bf(v.z); s.w = (short)f2bf(v.w);
  *(short4*)(xb + (size_t)i * 4) = s;
}

// ------------------------------------------- transpose + cast weights (D=1024)
__global__ __launch_bounds__(256) void k_trans_w(
    const float* __restrict__ W0, const float* __restrict__ W1,
    const float* __restrict__ W2, const float* __restrict__ W3,
    u16* __restrict__ T0, u16* __restrict__ T1, u16* __restrict__ T2,
    u16* __restrict__ T3) {
  const float* W = blockIdx.z == 0 ? W0 : blockIdx.z == 1 ? W1 : blockIdx.z == 2 ? W2 : W3;
  u16* T = blockIdx.z == 0 ? T0 : blockIdx.z == 1 ? T1 : blockIdx.z == 2 ? T2 : T3;
  __shared__ float tile[32][33];
  int r0 = blockIdx.y * 32, c0 = blockIdx.x * 32;
  int tid = threadIdx.x;
  for (int i = tid; i < 1024; i += 256) {
    int r = i >> 5, c = i & 31;
    tile[r][c] = W[(size_t)(r0 + r) * 1024 + c0 + c];
  }
  __syncthreads();
  for (int i = tid; i < 1024; i += 256) {
    int r = i >> 5, c = i & 31;
    T[(size_t)(c0 + r) * 1024 + r0 + c] = f2bf(tile[c][r]);
  }
}

// -------------------- k_proj: 256x128 tile, BK=32, 3-slot counted rotation
// R11 post-mortem model: all kernels pinned at ~6.3TB/s vector-mem REQUEST
// ceiling; dur ~= staged_bytes/6.3TB/s when >=2 blk/CU keep demand continuous.
// 256x128 cuts staged traffic 402->295MB vs 128^2 while keeping 2 blk/CU
// (72KB LDS). Proven race-safe rotation: counted vmcnt + lgkmcnt(0) drained
// with it before every barrier (R7 WAR fix). 6 loads/stage -> vmcnt(6).
__global__ __launch_bounds__(256) void k_proj(
    const u16* __restrict__ xb, const u16* __restrict__ WqT,
    const u16* __restrict__ WkT, const u16* __restrict__ WvT,
    const float* __restrict__ bq, const float* __restrict__ bk,
    const float* __restrict__ bv, u16* __restrict__ qh, u16* __restrict__ kh,
    u16* __restrict__ vh, u16* __restrict__ vT) {
  __shared__ __align__(16) u16 As[3 * 256 * 32];   // 48KB
  __shared__ __align__(16) u16 Bs[3 * 128 * 32];   // 24KB
  const int m0 = blockIdx.x * 256, n0 = blockIdx.y * 128;
  const int which = blockIdx.z;
  const u16* Ag = xb + (size_t)m0 * 1024;
  const u16* Bg = (which == 0 ? WqT : which == 1 ? WkT : WvT) + (size_t)n0 * 1024;
  const float* bias = which == 0 ? bq : which == 1 ? bk : bv;
  const int tid = threadIdx.x, lane = tid & 63, w = tid >> 6;
  const int wm = w >> 1, wn = w & 1, fr = lane & 15, fg = lane >> 4;

  f32x4 acc[8][4];
#pragma unroll
  for (int i = 0; i < 8; ++i)
#pragma unroll
    for (int j = 0; j < 4; ++j) acc[i][j] = f32x4{0.f, 0.f, 0.f, 0.f};

  auto stage = [&](int t, int slot) {
    u16* as = As + slot * 8192;
    u16* bs = Bs + slot * 4096;
#pragma unroll
    for (int L = 0; L < 4; ++L) {
      int q = L * 256 + tid;               // A: 1024 chunks (256 rows x 4)
      int row = q >> 2, c = q & 3;
      GLDS16(Ag + (size_t)row * 1024 + t * 32 + c * 8, as + q * 8);
    }
#pragma unroll
    for (int L = 0; L < 2; ++L) {
      int q = L * 256 + tid;               // B: 512 chunks (128 rows x 4)
      int row = q >> 2, c = q & 3;
      GLDS16(Bg + (size_t)row * 1024 + t * 32 + c * 8, bs + q * 8);
    }
  };
  auto compute = [&](int slot) {
    const u16* as = As + slot * 8192;
    const u16* bs = Bs + slot * 4096;
    short8 bf_[4];
#pragma unroll
    for (int j = 0; j < 4; ++j) {
      int row = wn * 64 + j * 16 + fr;
      bf_[j] = *(const short8*)(bs + row * 32 + fg * 8);
    }
    short8 af_[8];
#pragma unroll
    for (int i = 0; i < 8; ++i) {
      int row = wm * 128 + i * 16 + fr;
      af_[i] = *(const short8*)(as + row * 32 + fg * 8);
    }
#pragma unroll
    for (int i = 0; i < 8; ++i)
#pragma unroll
      for (int j = 0; j < 4; ++j)
        acc[i][j] = __builtin_amdgcn_mfma_f32_16x16x32_bf16(af_[i], bf_[j],
                                                            acc[i][j], 0, 0, 0);
  };

  const int NS = 32;  // K=1024 / BK=32
  stage(0, 0);
  stage(1, 1);
  int cs = 0, ss = 2;
  for (int t = 0; t + 2 < NS; ++t) {
    asm volatile("s_waitcnt vmcnt(6) lgkmcnt(0)" ::: "memory");
    __builtin_amdgcn_s_barrier();
    asm volatile("" ::: "memory");
    stage(t + 2, ss);
    compute(cs);
    cs = cs == 2 ? 0 : cs + 1;
    ss = ss == 2 ? 0 : ss + 1;
  }
  asm volatile("s_waitcnt vmcnt(6) lgkmcnt(0)" ::: "memory");
  __builtin_amdgcn_s_barrier();
  asm volatile("" ::: "memory");
  compute(cs);
  cs = cs == 2 ? 0 : cs + 1;
  asm volatile("s_waitcnt vmcnt(0) lgkmcnt(0)" ::: "memory");
  __builtin_amdgcn_s_barrier();
  asm volatile("" ::: "memory");
  compute(cs);

  // ---- epilogue ----
#pragma unroll
  for (int f = 0; f < 8; ++f)
#pragma unroll
    for (int j2 = 0; j2 < 4; ++j2) {
      int n = n0 + wn * 64 + j2 * 16 + fr;
      float bb = bias[n];
      int h = n >> 6, dc = n & 63;
#pragma unroll
      for (int r = 0; r < 4; ++r) {
        int m = m0 + wm * 128 + f * 16 + fg * 4 + r;
        int b = m >> 10, nr = m & 1023;
        int z = b * 16 + h;
        float val = acc[f][j2][r] + bb;
        u16 bv16 = f2bf(val);
        if (which == 0) {
          qh[((size_t)z * 1024 + nr) * 64 + dc] = bv16;
        } else if (which == 1) {
          kh[((size_t)z * 1024 + nr) * 64 + dc] = bv16;
        } else {
          vh[((size_t)z * 1024 + nr) * 64 + dc] = bv16;
          vT[((size_t)z * 64 + dc) * 1024 + nr] = bv16;
        }
      }
    }
}

// 3-slot pipelined core for k_final (proven config, unchanged)
__device__ __forceinline__ void core128x64_p3(const u16* __restrict__ A,
                                              const u16* __restrict__ Bt, int K,
                                              f32x4 (&acc)[2][4], u16* As,
                                              u16* Bs) {
  const int tid = threadIdx.x;
  const int lane = tid & 63;
  const int w = tid >> 6;
  const int fr = lane & 15, fg = lane >> 4;
  const int sr = tid >> 2, sc = (tid & 3) * 8;
#pragma unroll
  for (int i = 0; i < 2; ++i)
#pragma unroll
    for (int j = 0; j < 4; ++j) acc[i][j] = f32x4{0.f, 0.f, 0.f, 0.f};

  auto stage = [&](int t, int slot) {
    u16* as = As + slot * 4096;
    u16* bs = Bs + slot * 2048;
    const int k0 = t * 32 + sc;
    GLDS16(A + (size_t)sr * K + k0, as + tid * 8);
    GLDS16(A + (size_t)(sr + 64) * K + k0, as + (256 + tid) * 8);
    GLDS16(Bt + (size_t)sr * K + k0, bs + tid * 8);
  };
  auto compute = [&](int slot) {
    const u16* as = As + slot * 4096;
    const u16* bs = Bs + slot * 2048;
    short8 af[2], bfv[4];
#pragma unroll
    for (int i = 0; i < 2; ++i)
      af[i] = *(const short8*)(as + (w * 32 + i * 16 + fr) * 32 + fg * 8);
#pragma unroll
    for (int j = 0; j < 4; ++j)
      bfv[j] = *(const short8*)(bs + (j * 16 + fr) * 32 + fg * 8);
#pragma unroll
    for (int i = 0; i < 2; ++i)
#pragma unroll
      for (int j = 0; j < 4; ++j)
        acc[i][j] = __builtin_amdgcn_mfma_f32_16x16x32_bf16(af[i], bfv[j],
                                                            acc[i][j], 0, 0, 0);
  };

  const int NS = K / 32;
  stage(0, 0);
  stage(1, 1);
  int cs = 0, ss = 2;
  for (int t = 0; t + 2 < NS; ++t) {
    asm volatile("s_waitcnt vmcnt(3) lgkmcnt(0)" ::: "memory");
    __builtin_amdgcn_s_barrier();
    asm volatile("" ::: "memory");
    stage(t + 2, ss);
    compute(cs);
    cs = cs == 2 ? 0 : cs + 1;
    ss = ss == 2 ? 0 : ss + 1;
  }
  asm volatile("s_waitcnt vmcnt(3) lgkmcnt(0)" ::: "memory");
  __builtin_amdgcn_s_barrier();
  asm volatile("" ::: "memory");
  compute(cs);
  cs = cs == 2 ? 0 : cs + 1;
  asm volatile("s_waitcnt vmcnt(0) lgkmcnt(0)" ::: "memory");
  __builtin_amdgcn_s_barrier();
  asm volatile("" ::: "memory");
  compute(cs);
}

// -------------------------------------------------------------- pass 1
// R12: QBLK=128 (4 waves x 32 rows, R4's 2-rt layout) + R5's no-max softmax.
// Halves K/V staging traffic (262->131MB). LDS 32KB -> ~4 blk/CU.
__global__ __launch_bounds__(256) void k_pass1(
    const u16* __restrict__ qh, const u16* __restrict__ kh,
    const u16* __restrict__ vT, u16* __restrict__ P1T,
    u16* __restrict__ P1h, float* __restrict__ mlinv) {
  __shared__ __align__(16) u16 Ks[64 * 64];
  __shared__ __align__(16) u16 Vs[64 * 64];
  __shared__ __align__(16) u16 Ps[4][32 * 64];
  const int z = blockIdx.y;
  const int m0 = blockIdx.x * 128;
  const int tid = threadIdx.x, lane = tid & 63, w = tid >> 6;
  const int fr = lane & 15, fg = lane >> 4;
  const int row0 = m0 + w * 32;
  const u16* qbase = qh + (size_t)z * 65536;
  const u16* kbase = kh + (size_t)z * 65536;
  const u16* vbase = vT + (size_t)z * 65536;
  u16* myP = &Ps[w][0];

  short8 qf[2][2];
#pragma unroll
  for (int rt = 0; rt < 2; ++rt)
#pragma unroll
    for (int kc = 0; kc < 2; ++kc)
      qf[rt][kc] = *(const short8*)(qbase + (size_t)(row0 + rt * 16 + fr) * 64 +
                                    (kc * 4 + fg) * 8);

  f32x4 o[2][4];
  float rs[2][4];
#pragma unroll
  for (int rt = 0; rt < 2; ++rt)
#pragma unroll
    for (int ct = 0; ct < 4; ++ct) o[rt][ct] = f32x4{0.f, 0.f, 0.f, 0.f};
#pragma unroll
  for (int rt = 0; rt < 2; ++rt)
#pragma unroll
    for (int r = 0; r < 4; ++r) rs[rt][r] = 0.f;

  for (int t = 0; t < 16; ++t) {
    const int kv0 = t * 64;
#pragma unroll
    for (int it = 0; it < 2; ++it) {
      int idx = it * 256 + tid;
      int row = idx >> 3, cc = idx & 7;
      GLDS16(kbase + (size_t)(kv0 + row) * 64 + ((cc ^ (row & 7)) * 8),
             Ks + idx * 8);
      GLDS16(vbase + (size_t)row * 1024 + kv0 + ((cc ^ (row & 7)) * 8),
             Vs + idx * 8);
    }
    __syncthreads();
    // S = q @ k^T ; P = exp2(S*c) ; per-lane partial row-sums
#pragma unroll
    for (int ct = 0; ct < 4; ++ct) {
      int krow = ct * 16 + fr;
      short8 k0 = *(const short8*)(Ks + krow * 64 + ((fg ^ (krow & 7)) * 8));
      short8 k1 = *(const short8*)(Ks + krow * 64 + (((4 + fg) ^ (krow & 7)) * 8));
      int pcol = ct * 16 + fr;
      int cc = pcol >> 3;
#pragma unroll
      for (int rt = 0; rt < 2; ++rt) {
        f32x4 s = __builtin_amdgcn_mfma_f32_16x16x32_bf16(
            qf[rt][0], k0, f32x4{0.f, 0.f, 0.f, 0.f}, 0, 0, 0);
        s = __builtin_amdgcn_mfma_f32_16x16x32_bf16(qf[rt][1], k1, s, 0, 0, 0);
#pragma unroll
        for (int r = 0; r < 4; ++r) {
          float e = __builtin_exp2f(s[r] * EXP_SCALE);
          rs[rt][r] += e;
          int prow = rt * 16 + fg * 4 + r;
          myP[prow * 64 + ((cc ^ (prow & 7)) * 8) + (pcol & 7)] = f2bf(e);
        }
      }
    }
    asm volatile("s_waitcnt lgkmcnt(0)" ::: "memory");
    // ---- O += P @ V ----
#pragma unroll
    for (int rt = 0; rt < 2; ++rt) {
      int prow = rt * 16 + fr;
      short8 p0 = *(const short8*)(myP + prow * 64 + ((fg ^ (prow & 7)) * 8));
      short8 p1 = *(const short8*)(myP + prow * 64 + (((4 + fg) ^ (prow & 7)) * 8));
#pragma unroll
      for (int ct = 0; ct < 4; ++ct) {
        int vrow = ct * 16 + fr;
        short8 v0 = *(const short8*)(Vs + vrow * 64 + ((fg ^ (vrow & 7)) * 8));
        short8 v1 = *(const short8*)(Vs + vrow * 64 + (((4 + fg) ^ (vrow & 7)) * 8));
        o[rt][ct] = __builtin_amdgcn_mfma_f32_16x16x32_bf16(p0, v0, o[rt][ct], 0, 0, 0);
        o[rt][ct] = __builtin_amdgcn_mfma_f32_16x16x32_bf16(p1, v1, o[rt][ct], 0, 0, 0);
      }
    }
    __syncthreads();
  }
  // ---- deferred row-sum reduce over the 16 fr lanes ----
#pragma unroll
  for (int off = 1; off < 16; off <<= 1)
#pragma unroll
    for (int rt = 0; rt < 2; ++rt)
#pragma unroll
      for (int r = 0; r < 4; ++r) rs[rt][r] += __shfl_xor(rs[rt][r], off, 64);
  float linv[2][4];
#pragma unroll
  for (int rt = 0; rt < 2; ++rt)
#pragma unroll
    for (int r = 0; r < 4; ++r) linv[rt][r] = 1.f / rs[rt][r];
  // ---- epilogue: normalize, write P1T + P1h + stats ----
#pragma unroll
  for (int rt = 0; rt < 2; ++rt)
#pragma unroll
    for (int ct = 0; ct < 4; ++ct) {
      union { u16 u[4]; short4 s4; } pk;
#pragma unroll
      for (int r = 0; r < 4; ++r) {
        u16 b_ = f2bf(o[rt][ct][r] * linv[rt][r]);
        pk.u[r] = b_;
        myP[(rt * 16 + fg * 4 + r) * 64 + ct * 16 + fr] = b_;  // linear stage
      }
      *(short4*)(P1T + ((size_t)z * 64 + ct * 16 + fr) * 1024 + row0 +
                 rt * 16 + fg * 4) = pk.s4;
    }
  asm volatile("s_waitcnt lgkmcnt(0)" ::: "memory");
  {
    int r_ = lane >> 1, hb = lane & 1;
#pragma unroll
    for (int c = 0; c < 4; ++c) {
      int ch = hb * 4 + c;
      int4 vv = *(const int4*)(myP + r_ * 64 + ch * 8);
      *(int4*)(P1h + ((size_t)z * 1024 + row0 + r_) * 64 + ch * 8) = vv;
    }
  }
  if (fr == 0) {
#pragma unroll
    for (int rt = 0; rt < 2; ++rt)
#pragma unroll
      for (int r = 0; r < 4; ++r)
        mlinv[(size_t)z * 1024 + row0 + rt * 16 + fg * 4 + r] = linv[rt][r];
  }
}

// -------------------------------------------------------------- pass 2
// QBLK=128; recompute S (same frags/order), P = exp2(S*c)*linv, O2 += P@P1;
// fused epilogue OH = cw0*v + cw1*P1 + cw2*O2, coalesced.
__global__ __launch_bounds__(256) void k_pass2(
    const u16* __restrict__ qh, const u16* __restrict__ kh,
    const u16* __restrict__ P1T, const u16* __restrict__ vh,
    const u16* __restrict__ P1h, const float* __restrict__ mlinv,
    const float* __restrict__ w0, const float* __restrict__ w1,
    const float* __restrict__ wK, u16* __restrict__ OH) {
  __shared__ __align__(16) u16 Ks[64 * 64];
  __shared__ __align__(16) u16 Ts[64 * 64];
  __shared__ __align__(16) u16 Ps[4][32 * 64];
  const int z = blockIdx.y;
  const int m0 = blockIdx.x * 128;
  const int tid = threadIdx.x, lane = tid & 63, w = tid >> 6;
  const int fr = lane & 15, fg = lane >> 4;
  const int row0 = m0 + w * 32;
  const int h = z & 15, b = z >> 4;
  const float cw0 = w0[h], cw1 = w1[h] - wK[h], cw2 = 2.f * wK[h];
  const u16* qbase = qh + (size_t)z * 65536;
  const u16* kbase = kh + (size_t)z * 65536;
  const u16* tbase = P1T + (size_t)z * 65536;
  u16* myP = &Ps[w][0];

  short8 qf[2][2];
#pragma unroll
  for (int rt = 0; rt < 2; ++rt)
#pragma unroll
    for (int kc = 0; kc < 2; ++kc)
      qf[rt][kc] = *(const short8*)(qbase + (size_t)(row0 + rt * 16 + fr) * 64 +
                                    (kc * 4 + fg) * 8);
  float lrow[2][4];
#pragma unroll
  for (int rt = 0; rt < 2; ++rt)
#pragma unroll
    for (int r = 0; r < 4; ++r)
      lrow[rt][r] = mlinv[(size_t)z * 1024 + row0 + rt * 16 + fg * 4 + r];
  f32x4 o[2][4];
#pragma unroll
  for (int rt = 0; rt < 2; ++rt)
#pragma unroll
    for (int ct = 0; ct < 4; ++ct) o[rt][ct] = f32x4{0.f, 0.f, 0.f, 0.f};

  for (int t = 0; t < 16; ++t) {
    const int kv0 = t * 64;
#pragma unroll
    for (int it = 0; it < 2; ++it) {
      int idx = it * 256 + tid;
      int row = idx >> 3, cc = idx & 7;
      GLDS16(kbase + (size_t)(kv0 + row) * 64 + ((cc ^ (row & 7)) * 8),
             Ks + idx * 8);
      GLDS16(tbase + (size_t)row * 1024 + kv0 + ((cc ^ (row & 7)) * 8),
             Ts + idx * 8);
    }
    __syncthreads();
#pragma unroll
    for (int ct = 0; ct < 4; ++ct) {
      int krow = ct * 16 + fr;
      short8 k0 = *(const short8*)(Ks + krow * 64 + ((fg ^ (krow & 7)) * 8));
      short8 k1 = *(const short8*)(Ks + krow * 64 + (((4 + fg) ^ (krow & 7)) * 8));
      int pcol = ct * 16 + fr;
      int cc = pcol >> 3;
#pragma unroll
      for (int rt = 0; rt < 2; ++rt) {
        f32x4 s = __builtin_amdgcn_mfma_f32_16x16x32_bf16(
            qf[rt][0], k0, f32x4{0.f, 0.f, 0.f, 0.f}, 0, 0, 0);
        s = __builtin_amdgcn_mfma_f32_16x16x32_bf16(qf[rt][1], k1, s, 0, 0, 0);
#pragma unroll
        for (int r = 0; r < 4; ++r) {
          float p = __builtin_exp2f(s[r] * EXP_SCALE) * lrow[rt][r];
          int prow = rt * 16 + fg * 4 + r;
          myP[prow * 64 + ((cc ^ (prow & 7)) * 8) + (pcol & 7)] = f2bf(p);
        }
      }
    }
    asm volatile("s_waitcnt lgkmcnt(0)" ::: "memory");
#pragma unroll
    for (int rt = 0; rt < 2; ++rt) {
      int prow = rt * 16 + fr;
      short8 p0 = *(const short8*)(myP + prow * 64 + ((fg ^ (prow & 7)) * 8));
      short8 p1 = *(const short8*)(myP + prow * 64 + (((4 + fg) ^ (prow & 7)) * 8));
#pragma unroll
      for (int ct = 0; ct < 4; ++ct) {
        int vrow = ct * 16 + fr;
        short8 v0 = *(const short8*)(Ts + vrow * 64 + ((fg ^ (vrow & 7)) * 8));
        short8 v1 = *(const short8*)(Ts + vrow * 64 + (((4 + fg) ^ (vrow & 7)) * 8));
        o[rt][ct] = __builtin_amdgcn_mfma_f32_16x16x32_bf16(p0, v0, o[rt][ct], 0, 0, 0);
        o[rt][ct] = __builtin_amdgcn_mfma_f32_16x16x32_bf16(p1, v1, o[rt][ct], 0, 0, 0);
      }
    }
    __syncthreads();
  }
  // ---- epilogue: OH = cw0*v + cw1*P1 + cw2*O2, coalesced via LDS stage ----
#pragma unroll
  for (int rt = 0; rt < 2; ++rt)
#pragma unroll
    for (int ct = 0; ct < 4; ++ct)
#pragma unroll
      for (int r = 0; r < 4; ++r)
        myP[(rt * 16 + fg * 4 + r) * 64 + ct * 16 + fr] = f2bf(o[rt][ct][r]);
  asm volatile("s_waitcnt lgkmcnt(0)" ::: "memory");
  {
    int r_ = lane >> 1, hb = lane & 1;
    const u16* vp = vh + ((size_t)z * 1024 + row0 + r_) * 64;
    const u16* pp = P1h + ((size_t)z * 1024 + row0 + r_) * 64;
    u16* op = OH + ((size_t)b * 1024 + row0 + r_) * 1024 + h * 64;
#pragma unroll
    for (int c = 0; c < 4; ++c) {
      int ch = hb * 4 + c;
      short8 pv = *(const short8*)(myP + r_ * 64 + ch * 8);
      short8 vv = *(const short8*)(vp + ch * 8);
      short8 p1 = *(const short8*)(pp + ch * 8);
      short8 res;
#pragma unroll
      for (int e = 0; e < 8; ++e) {
        float f = cw0 * bf2f((u16)vv[e]) + cw1 * bf2f((u16)p1[e]) +
                  cw2 * bf2f((u16)pv[e]);
        res[e] = (short)f2bf(f);
      }
      *(short8*)(op + ch * 8) = res;
    }
  }
}

// ------------------------------------------------- final: out = OH @ Wo + bo
__global__ __launch_bounds__(256) void k_final(const u16* __restrict__ OH,
                                               const u16* __restrict__ WoT,
                                               const float* __restrict__ bo,
                                               float* __restrict__ out) {
  __shared__ __align__(16) u16 As[3 * 128 * 32];
  __shared__ __align__(16) u16 Bs[3 * 64 * 32];
  const int li = blockIdx.x + 32 * blockIdx.y;
  const int cx = li & 7, jb = li >> 3;
  const int m0 = (cx * 4 + (jb & 3)) * 128;
  const int n0 = (jb >> 2) * 64;
  f32x4 acc[2][4];
  core128x64_p3(OH + (size_t)m0 * 1024, WoT + (size_t)n0 * 1024, 1024, acc, As, Bs);
  const int tid = threadIdx.x, lane = tid & 63, w = tid >> 6;
  const int fr = lane & 15, fg = lane >> 4;
#pragma unroll
  for (int i = 0; i < 2; ++i)
#pragma unroll
    for (int j2 = 0; j2 < 4; ++j2) {
      int n = n0 + j2 * 16 + fr;
      float bb = bo[n];
#pragma unroll
      for (int r = 0; r < 4; ++r) {
        int m = m0 + w * 32 + i * 16 + fg * 4 + r;
        out[(size_t)m * 1024 + n] = acc[i][j2][r] + bb;
      }
    }
}

extern "C" void kernel_launch(void* const* d_in, const int* in_sizes, int n_in,
                              void* d_out, int out_size, void* d_ws,
                              size_t ws_size, hipStream_t stream) {
  const float* x = (const float*)d_in[0];
  const float* Wq = (const float*)d_in[1];
  const float* bq = (const float*)d_in[2];
  const float* Wk = (const float*)d_in[3];
  const float* bk = (const float*)d_in[4];
  const float* Wv = (const float*)d_in[5];
  const float* bv = (const float*)d_in[6];
  const float* Wo = (const float*)d_in[7];
  const float* bo = (const float*)d_in[8];
  const float* w0 = (const float*)d_in[9];
  const float* w1 = (const float*)d_in[10];
  const float* wK = (const float*)d_in[11];
  float* out = (float*)d_out;

  char* ws = (char*)d_ws;
  const size_t MB = 1ull << 20;
  u16* xb  = (u16*)(ws);             // 8 MiB
  u16* WqT = (u16*)(ws + 8 * MB);    // 2 MiB
  u16* WkT = (u16*)(ws + 10 * MB);   // 2 MiB
  u16* WvT = (u16*)(ws + 12 * MB);   // 2 MiB
  u16* WoT = (u16*)(ws + 14 * MB);   // 2 MiB
  u16* qh  = (u16*)(ws + 16 * MB);   // 8 MiB  [z][n][d]
  u16* kh  = (u16*)(ws + 24 * MB);   // 8 MiB  [z][n][d]
  u16* vh  = (u16*)(ws + 32 * MB);   // 8 MiB  [z][n][d]
  u16* vT  = (u16*)(ws + 40 * MB);   // 8 MiB  [z][d][n]
  u16* P1T = (u16*)(ws + 48 * MB);   // 8 MiB  [z][d][n]
  u16* P1h = (u16*)(ws + 56 * MB);   // 8 MiB  [z][n][d]
  u16* OH  = (u16*)(ws + 64 * MB);   // 8 MiB  [b][n][D]
  float* mlinv = (float*)(ws + 72 * MB);  // 256 KiB [z][n]

  hipLaunchKernelGGL(k_cast_x, dim3(4096), dim3(256), 0, stream, x, xb);
  hipLaunchKernelGGL(k_trans_w, dim3(32, 32, 4), dim3(256), 0, stream, Wq, Wk,
                     Wv, Wo, WqT, WkT, WvT, WoT);
  hipLaunchKernelGGL(k_proj, dim3(16, 8, 3), dim3(256), 0, stream, xb, WqT, WkT,
                     WvT, bq, bk, bv, qh, kh, vh, vT);
  hipLaunchKernelGGL(k_pass1, dim3(8, 64), dim3(256), 0, stream, qh, kh, vT,
                     P1T, P1h, mlinv);
  hipLaunchKernelGGL(k_pass2, dim3(8, 64), dim3(256), 0, stream, qh, kh, P1T,
                     vh, P1h, mlinv, w0, w1, wK, OH);
  hipLaunchKernelGGL(k_final, dim3(32, 16), dim3(256), 0, stream, OH, WoT, bo,
                     out);
}

// Round 13
// 179.519 us; speedup vs baseline: 1.0409x; 1.0400x over previous
//
#include <hip/hip_runtime.h>

typedef unsigned short u16;
typedef unsigned int u32;
typedef __attribute__((ext_vector_type(8))) short short8;
typedef __attribute__((ext_vector_type(4))) float f32x4;

__device__ __forceinline__ u16 f2bf(float f) {
  union { float f; u32 u; } c; c.f = f;
  u32 u = c.u;
  u += 0x7fffu + ((u >> 16) & 1u);  // round-to-nearest-even
  return (u16)(u >> 16);
}
__device__ __forceinline__ float bf2f(u16 h) {
  union { u32 u; float f; } c; c.u = ((u32)h) << 16;
  return c.f;
}

// async global->LDS, 16B per lane; LDS dest must be linear in lane order
#define GLDS16(g, l)                                                          \
  __builtin_amdgcn_global_load_lds(                                           \
      (const __attribute__((address_space(1))) u32*)(g),                      \
      (__attribute__((address_space(3))) u32*)(l), 16, 0, 0)

// exp(x*0.125) == exp2(x * 0.125*log2(e))
#define EXP_SCALE 0.18033688011112042f

// ---------------------------------------------------------------- cast x
__global__ __launch_bounds__(256) void k_cast_x(const float* __restrict__ x,
                                                u16* __restrict__ xb) {
  int i = blockIdx.x * 256 + threadIdx.x;
  float4 v = ((const float4*)x)[i];
  short4 s;
  s.x = (short)f2bf(v.x); s.y = (short)f2bf(v.y);
  s.z = (short)f2bf(v.z); s.w = (short)f2bf(v.w);
  *(short4*)(xb + (size_t)i * 4) = s;
}

// ------------------------------------------- transpose + cast weights (D=1024)
__global__ __launch_bounds__(256) void k_trans_w(
    const float* __restrict__ W0, const float* __restrict__ W1,
    const float* __restrict__ W2, const float* __restrict__ W3,
    u16* __restrict__ T0, u16* __restrict__ T1, u16* __restrict__ T2,
    u16* __restrict__ T3) {
  const float* W = blockIdx.z == 0 ? W0 : blockIdx.z == 1 ? W1 : blockIdx.z == 2 ? W2 : W3;
  u16* T = blockIdx.z == 0 ? T0 : blockIdx.z == 1 ? T1 : blockIdx.z == 2 ? T2 : T3;
  __shared__ float tile[32][33];
  int r0 = blockIdx.y * 32, c0 = blockIdx.x * 32;
  int tid = threadIdx.x;
  for (int i = tid; i < 1024; i += 256) {
    int r = i >> 5, c = i & 31;
    tile[r][c] = W[(size_t)(r0 + r) * 1024 + c0 + c];
  }
  __syncthreads();
  for (int i = tid; i < 1024; i += 256) {
    int r = i >> 5, c = i & 31;
    T[(size_t)(c0 + r) * 1024 + r0 + c] = f2bf(tile[c][r]);
  }
}

// ----------- k_proj: 256x128 tile, BK=32, 3-slot rotation, 512 threads
// R13: resident-wave model (R5..R12 fit): staging BW ~= 0.55 TB/s per
// wave/CU, saturating ~6.3 TB/s at >=12 waves/CU. R12's 256-thr config had
// only ~6 resident waves/CU -> 3.4 TB/s. Same tile+rotation at 512 thr
// (8 waves/block, 2 blk/CU by LDS) restores ~12 waves/CU avg over the
// 384-block grid while keeping the reduced 295MB traffic.
// Race-safe discipline (R7): counted vmcnt + lgkmcnt(0) before EVERY barrier.
__global__ __launch_bounds__(512, 4) void k_proj(
    const u16* __restrict__ xb, const u16* __restrict__ WqT,
    const u16* __restrict__ WkT, const u16* __restrict__ WvT,
    const float* __restrict__ bq, const float* __restrict__ bk,
    const float* __restrict__ bv, u16* __restrict__ qh, u16* __restrict__ kh,
    u16* __restrict__ vh, u16* __restrict__ vT) {
  __shared__ __align__(16) u16 As[3 * 256 * 32];   // 48KB
  __shared__ __align__(16) u16 Bs[3 * 128 * 32];   // 24KB
  const int m0 = blockIdx.x * 256, n0 = blockIdx.y * 128;
  const int which = blockIdx.z;
  const u16* Ag = xb + (size_t)m0 * 1024;
  const u16* Bg = (which == 0 ? WqT : which == 1 ? WkT : WvT) + (size_t)n0 * 1024;
  const float* bias = which == 0 ? bq : which == 1 ? bk : bv;
  const int tid = threadIdx.x, lane = tid & 63, wid = tid >> 6;
  const int wm = wid >> 1, wn = wid & 1, fr = lane & 15, fg = lane >> 4;

  f32x4 acc[4][4];
#pragma unroll
  for (int i = 0; i < 4; ++i)
#pragma unroll
    for (int j = 0; j < 4; ++j) acc[i][j] = f32x4{0.f, 0.f, 0.f, 0.f};

  auto stage = [&](int t, int slot) {
    u16* as = As + slot * 8192;
    u16* bs = Bs + slot * 4096;
#pragma unroll
    for (int L = 0; L < 2; ++L) {
      int q = L * 512 + tid;               // A: 1024 chunks (256 rows x 4)
      int row = q >> 2, c = q & 3;
      GLDS16(Ag + (size_t)row * 1024 + t * 32 + c * 8, as + q * 8);
    }
    {
      int q = tid;                          // B: 512 chunks (128 rows x 4)
      int row = q >> 2, c = q & 3;
      GLDS16(Bg + (size_t)row * 1024 + t * 32 + c * 8, bs + q * 8);
    }
  };
  auto compute = [&](int slot) {
    const u16* as = As + slot * 8192;
    const u16* bs = Bs + slot * 4096;
    short8 bf_[4];
#pragma unroll
    for (int j = 0; j < 4; ++j) {
      int row = wn * 64 + j * 16 + fr;
      bf_[j] = *(const short8*)(bs + row * 32 + fg * 8);
    }
    short8 af_[4];
#pragma unroll
    for (int i = 0; i < 4; ++i) {
      int row = wm * 64 + i * 16 + fr;
      af_[i] = *(const short8*)(as + row * 32 + fg * 8);
    }
#pragma unroll
    for (int i = 0; i < 4; ++i)
#pragma unroll
      for (int j = 0; j < 4; ++j)
        acc[i][j] = __builtin_amdgcn_mfma_f32_16x16x32_bf16(af_[i], bf_[j],
                                                            acc[i][j], 0, 0, 0);
  };

  const int NS = 32;  // K=1024 / BK=32
  stage(0, 0);
  stage(1, 1);
  int cs = 0, ss = 2;
  for (int t = 0; t + 2 < NS; ++t) {
    asm volatile("s_waitcnt vmcnt(3) lgkmcnt(0)" ::: "memory");
    __builtin_amdgcn_s_barrier();
    asm volatile("" ::: "memory");
    stage(t + 2, ss);
    compute(cs);
    cs = cs == 2 ? 0 : cs + 1;
    ss = ss == 2 ? 0 : ss + 1;
  }
  asm volatile("s_waitcnt vmcnt(3) lgkmcnt(0)" ::: "memory");
  __builtin_amdgcn_s_barrier();
  asm volatile("" ::: "memory");
  compute(cs);
  cs = cs == 2 ? 0 : cs + 1;
  asm volatile("s_waitcnt vmcnt(0) lgkmcnt(0)" ::: "memory");
  __builtin_amdgcn_s_barrier();
  asm volatile("" ::: "memory");
  compute(cs);

  // ---- epilogue ----
#pragma unroll
  for (int f = 0; f < 4; ++f)
#pragma unroll
    for (int j2 = 0; j2 < 4; ++j2) {
      int n = n0 + wn * 64 + j2 * 16 + fr;
      float bb = bias[n];
      int h = n >> 6, dc = n & 63;
#pragma unroll
      for (int r = 0; r < 4; ++r) {
        int m = m0 + wm * 64 + f * 16 + fg * 4 + r;
        int b = m >> 10, nr = m & 1023;
        int z = b * 16 + h;
        float val = acc[f][j2][r] + bb;
        u16 bv16 = f2bf(val);
        if (which == 0) {
          qh[((size_t)z * 1024 + nr) * 64 + dc] = bv16;
        } else if (which == 1) {
          kh[((size_t)z * 1024 + nr) * 64 + dc] = bv16;
        } else {
          vh[((size_t)z * 1024 + nr) * 64 + dc] = bv16;
          vT[((size_t)z * 64 + dc) * 1024 + nr] = bv16;
        }
      }
    }
}

// 3-slot pipelined core for k_final (proven config, unchanged)
__device__ __forceinline__ void core128x64_p3(const u16* __restrict__ A,
                                              const u16* __restrict__ Bt, int K,
                                              f32x4 (&acc)[2][4], u16* As,
                                              u16* Bs) {
  const int tid = threadIdx.x;
  const int lane = tid & 63;
  const int w = tid >> 6;
  const int fr = lane & 15, fg = lane >> 4;
  const int sr = tid >> 2, sc = (tid & 3) * 8;
#pragma unroll
  for (int i = 0; i < 2; ++i)
#pragma unroll
    for (int j = 0; j < 4; ++j) acc[i][j] = f32x4{0.f, 0.f, 0.f, 0.f};

  auto stage = [&](int t, int slot) {
    u16* as = As + slot * 4096;
    u16* bs = Bs + slot * 2048;
    const int k0 = t * 32 + sc;
    GLDS16(A + (size_t)sr * K + k0, as + tid * 8);
    GLDS16(A + (size_t)(sr + 64) * K + k0, as + (256 + tid) * 8);
    GLDS16(Bt + (size_t)sr * K + k0, bs + tid * 8);
  };
  auto compute = [&](int slot) {
    const u16* as = As + slot * 4096;
    const u16* bs = Bs + slot * 2048;
    short8 af[2], bfv[4];
#pragma unroll
    for (int i = 0; i < 2; ++i)
      af[i] = *(const short8*)(as + (w * 32 + i * 16 + fr) * 32 + fg * 8);
#pragma unroll
    for (int j = 0; j < 4; ++j)
      bfv[j] = *(const short8*)(bs + (j * 16 + fr) * 32 + fg * 8);
#pragma unroll
    for (int i = 0; i < 2; ++i)
#pragma unroll
      for (int j = 0; j < 4; ++j)
        acc[i][j] = __builtin_amdgcn_mfma_f32_16x16x32_bf16(af[i], bfv[j],
                                                            acc[i][j], 0, 0, 0);
  };

  const int NS = K / 32;
  stage(0, 0);
  stage(1, 1);
  int cs = 0, ss = 2;
  for (int t = 0; t + 2 < NS; ++t) {
    asm volatile("s_waitcnt vmcnt(3) lgkmcnt(0)" ::: "memory");
    __builtin_amdgcn_s_barrier();
    asm volatile("" ::: "memory");
    stage(t + 2, ss);
    compute(cs);
    cs = cs == 2 ? 0 : cs + 1;
    ss = ss == 2 ? 0 : ss + 1;
  }
  asm volatile("s_waitcnt vmcnt(3) lgkmcnt(0)" ::: "memory");
  __builtin_amdgcn_s_barrier();
  asm volatile("" ::: "memory");
  compute(cs);
  cs = cs == 2 ? 0 : cs + 1;
  asm volatile("s_waitcnt vmcnt(0) lgkmcnt(0)" ::: "memory");
  __builtin_amdgcn_s_barrier();
  asm volatile("" ::: "memory");
  compute(cs);
}

// -------------------------------------------------------------- pass 1
// QBLK=128 (4 waves x 32 rows) + no-max softmax, deferred sum-reduce.
__global__ __launch_bounds__(256) void k_pass1(
    const u16* __restrict__ qh, const u16* __restrict__ kh,
    const u16* __restrict__ vT, u16* __restrict__ P1T,
    u16* __restrict__ P1h, float* __restrict__ mlinv) {
  __shared__ __align__(16) u16 Ks[64 * 64];
  __shared__ __align__(16) u16 Vs[64 * 64];
  __shared__ __align__(16) u16 Ps[4][32 * 64];
  const int z = blockIdx.y;
  const int m0 = blockIdx.x * 128;
  const int tid = threadIdx.x, lane = tid & 63, w = tid >> 6;
  const int fr = lane & 15, fg = lane >> 4;
  const int row0 = m0 + w * 32;
  const u16* qbase = qh + (size_t)z * 65536;
  const u16* kbase = kh + (size_t)z * 65536;
  const u16* vbase = vT + (size_t)z * 65536;
  u16* myP = &Ps[w][0];

  short8 qf[2][2];
#pragma unroll
  for (int rt = 0; rt < 2; ++rt)
#pragma unroll
    for (int kc = 0; kc < 2; ++kc)
      qf[rt][kc] = *(const short8*)(qbase + (size_t)(row0 + rt * 16 + fr) * 64 +
                                    (kc * 4 + fg) * 8);

  f32x4 o[2][4];
  float rs[2][4];
#pragma unroll
  for (int rt = 0; rt < 2; ++rt)
#pragma unroll
    for (int ct = 0; ct < 4; ++ct) o[rt][ct] = f32x4{0.f, 0.f, 0.f, 0.f};
#pragma unroll
  for (int rt = 0; rt < 2; ++rt)
#pragma unroll
    for (int r = 0; r < 4; ++r) rs[rt][r] = 0.f;

  for (int t = 0; t < 16; ++t) {
    const int kv0 = t * 64;
#pragma unroll
    for (int it = 0; it < 2; ++it) {
      int idx = it * 256 + tid;
      int row = idx >> 3, cc = idx & 7;
      GLDS16(kbase + (size_t)(kv0 + row) * 64 + ((cc ^ (row & 7)) * 8),
             Ks + idx * 8);
      GLDS16(vbase + (size_t)row * 1024 + kv0 + ((cc ^ (row & 7)) * 8),
             Vs + idx * 8);
    }
    __syncthreads();
    // S = q @ k^T ; P = exp2(S*c) ; per-lane partial row-sums
#pragma unroll
    for (int ct = 0; ct < 4; ++ct) {
      int krow = ct * 16 + fr;
      short8 k0 = *(const short8*)(Ks + krow * 64 + ((fg ^ (krow & 7)) * 8));
      short8 k1 = *(const short8*)(Ks + krow * 64 + (((4 + fg) ^ (krow & 7)) * 8));
      int pcol = ct * 16 + fr;
      int cc = pcol >> 3;
#pragma unroll
      for (int rt = 0; rt < 2; ++rt) {
        f32x4 s = __builtin_amdgcn_mfma_f32_16x16x32_bf16(
            qf[rt][0], k0, f32x4{0.f, 0.f, 0.f, 0.f}, 0, 0, 0);
        s = __builtin_amdgcn_mfma_f32_16x16x32_bf16(qf[rt][1], k1, s, 0, 0, 0);
#pragma unroll
        for (int r = 0; r < 4; ++r) {
          float e = __builtin_exp2f(s[r] * EXP_SCALE);
          rs[rt][r] += e;
          int prow = rt * 16 + fg * 4 + r;
          myP[prow * 64 + ((cc ^ (prow & 7)) * 8) + (pcol & 7)] = f2bf(e);
        }
      }
    }
    asm volatile("s_waitcnt lgkmcnt(0)" ::: "memory");
    // ---- O += P @ V ----
#pragma unroll
    for (int rt = 0; rt < 2; ++rt) {
      int prow = rt * 16 + fr;
      short8 p0 = *(const short8*)(myP + prow * 64 + ((fg ^ (prow & 7)) * 8));
      short8 p1 = *(const short8*)(myP + prow * 64 + (((4 + fg) ^ (prow & 7)) * 8));
#pragma unroll
      for (int ct = 0; ct < 4; ++ct) {
        int vrow = ct * 16 + fr;
        short8 v0 = *(const short8*)(Vs + vrow * 64 + ((fg ^ (vrow & 7)) * 8));
        short8 v1 = *(const short8*)(Vs + vrow * 64 + (((4 + fg) ^ (vrow & 7)) * 8));
        o[rt][ct] = __builtin_amdgcn_mfma_f32_16x16x32_bf16(p0, v0, o[rt][ct], 0, 0, 0);
        o[rt][ct] = __builtin_amdgcn_mfma_f32_16x16x32_bf16(p1, v1, o[rt][ct], 0, 0, 0);
      }
    }
    __syncthreads();
  }
  // ---- deferred row-sum reduce over the 16 fr lanes ----
#pragma unroll
  for (int off = 1; off < 16; off <<= 1)
#pragma unroll
    for (int rt = 0; rt < 2; ++rt)
#pragma unroll
      for (int r = 0; r < 4; ++r) rs[rt][r] += __shfl_xor(rs[rt][r], off, 64);
  float linv[2][4];
#pragma unroll
  for (int rt = 0; rt < 2; ++rt)
#pragma unroll
    for (int r = 0; r < 4; ++r) linv[rt][r] = 1.f / rs[rt][r];
  // ---- epilogue: normalize, write P1T + P1h + stats ----
#pragma unroll
  for (int rt = 0; rt < 2; ++rt)
#pragma unroll
    for (int ct = 0; ct < 4; ++ct) {
      union { u16 u[4]; short4 s4; } pk;
#pragma unroll
      for (int r = 0; r < 4; ++r) {
        u16 b_ = f2bf(o[rt][ct][r] * linv[rt][r]);
        pk.u[r] = b_;
        myP[(rt * 16 + fg * 4 + r) * 64 + ct * 16 + fr] = b_;  // linear stage
      }
      *(short4*)(P1T + ((size_t)z * 64 + ct * 16 + fr) * 1024 + row0 +
                 rt * 16 + fg * 4) = pk.s4;
    }
  asm volatile("s_waitcnt lgkmcnt(0)" ::: "memory");
  {
    int r_ = lane >> 1, hb = lane & 1;
#pragma unroll
    for (int c = 0; c < 4; ++c) {
      int ch = hb * 4 + c;
      int4 vv = *(const int4*)(myP + r_ * 64 + ch * 8);
      *(int4*)(P1h + ((size_t)z * 1024 + row0 + r_) * 64 + ch * 8) = vv;
    }
  }
  if (fr == 0) {
#pragma unroll
    for (int rt = 0; rt < 2; ++rt)
#pragma unroll
      for (int r = 0; r < 4; ++r)
        mlinv[(size_t)z * 1024 + row0 + rt * 16 + fg * 4 + r] = linv[rt][r];
  }
}

// -------------------------------------------------------------- pass 2
__global__ __launch_bounds__(256) void k_pass2(
    const u16* __restrict__ qh, const u16* __restrict__ kh,
    const u16* __restrict__ P1T, const u16* __restrict__ vh,
    const u16* __restrict__ P1h, const float* __restrict__ mlinv,
    const float* __restrict__ w0, const float* __restrict__ w1,
    const float* __restrict__ wK, u16* __restrict__ OH) {
  __shared__ __align__(16) u16 Ks[64 * 64];
  __shared__ __align__(16) u16 Ts[64 * 64];
  __shared__ __align__(16) u16 Ps[4][32 * 64];
  const int z = blockIdx.y;
  const int m0 = blockIdx.x * 128;
  const int tid = threadIdx.x, lane = tid & 63, w = tid >> 6;
  const int fr = lane & 15, fg = lane >> 4;
  const int row0 = m0 + w * 32;
  const int h = z & 15, b = z >> 4;
  const float cw0 = w0[h], cw1 = w1[h] - wK[h], cw2 = 2.f * wK[h];
  const u16* qbase = qh + (size_t)z * 65536;
  const u16* kbase = kh + (size_t)z * 65536;
  const u16* tbase = P1T + (size_t)z * 65536;
  u16* myP = &Ps[w][0];

  short8 qf[2][2];
#pragma unroll
  for (int rt = 0; rt < 2; ++rt)
#pragma unroll
    for (int kc = 0; kc < 2; ++kc)
      qf[rt][kc] = *(const short8*)(qbase + (size_t)(row0 + rt * 16 + fr) * 64 +
                                    (kc * 4 + fg) * 8);
  float lrow[2][4];
#pragma unroll
  for (int rt = 0; rt < 2; ++rt)
#pragma unroll
    for (int r = 0; r < 4; ++r)
      lrow[rt][r] = mlinv[(size_t)z * 1024 + row0 + rt * 16 + fg * 4 + r];
  f32x4 o[2][4];
#pragma unroll
  for (int rt = 0; rt < 2; ++rt)
#pragma unroll
    for (int ct = 0; ct < 4; ++ct) o[rt][ct] = f32x4{0.f, 0.f, 0.f, 0.f};

  for (int t = 0; t < 16; ++t) {
    const int kv0 = t * 64;
#pragma unroll
    for (int it = 0; it < 2; ++it) {
      int idx = it * 256 + tid;
      int row = idx >> 3, cc = idx & 7;
      GLDS16(kbase + (size_t)(kv0 + row) * 64 + ((cc ^ (row & 7)) * 8),
             Ks + idx * 8);
      GLDS16(tbase + (size_t)row * 1024 + kv0 + ((cc ^ (row & 7)) * 8),
             Ts + idx * 8);
    }
    __syncthreads();
#pragma unroll
    for (int ct = 0; ct < 4; ++ct) {
      int krow = ct * 16 + fr;
      short8 k0 = *(const short8*)(Ks + krow * 64 + ((fg ^ (krow & 7)) * 8));
      short8 k1 = *(const short8*)(Ks + krow * 64 + (((4 + fg) ^ (krow & 7)) * 8));
      int pcol = ct * 16 + fr;
      int cc = pcol >> 3;
#pragma unroll
      for (int rt = 0; rt < 2; ++rt) {
        f32x4 s = __builtin_amdgcn_mfma_f32_16x16x32_bf16(
            qf[rt][0], k0, f32x4{0.f, 0.f, 0.f, 0.f}, 0, 0, 0);
        s = __builtin_amdgcn_mfma_f32_16x16x32_bf16(qf[rt][1], k1, s, 0, 0, 0);
#pragma unroll
        for (int r = 0; r < 4; ++r) {
          float p = __builtin_exp2f(s[r] * EXP_SCALE) * lrow[rt][r];
          int prow = rt * 16 + fg * 4 + r;
          myP[prow * 64 + ((cc ^ (prow & 7)) * 8) + (pcol & 7)] = f2bf(p);
        }
      }
    }
    asm volatile("s_waitcnt lgkmcnt(0)" ::: "memory");
#pragma unroll
    for (int rt = 0; rt < 2; ++rt) {
      int prow = rt * 16 + fr;
      short8 p0 = *(const short8*)(myP + prow * 64 + ((fg ^ (prow & 7)) * 8));
      short8 p1 = *(const short8*)(myP + prow * 64 + (((4 + fg) ^ (prow & 7)) * 8));
#pragma unroll
      for (int ct = 0; ct < 4; ++ct) {
        int vrow = ct * 16 + fr;
        short8 v0 = *(const short8*)(Ts + vrow * 64 + ((fg ^ (vrow & 7)) * 8));
        short8 v1 = *(const short8*)(Ts + vrow * 64 + (((4 + fg) ^ (vrow & 7)) * 8));
        o[rt][ct] = __builtin_amdgcn_mfma_f32_16x16x32_bf16(p0, v0, o[rt][ct], 0, 0, 0);
        o[rt][ct] = __builtin_amdgcn_mfma_f32_16x16x32_bf16(p1, v1, o[rt][ct], 0, 0, 0);
      }
    }
    __syncthreads();
  }
  // ---- epilogue: OH = cw0*v + cw1*P1 + cw2*O2, coalesced via LDS stage ----
#pragma unroll
  for (int rt = 0; rt < 2; ++rt)
#pragma unroll
    for (int ct = 0; ct < 4; ++ct)
#pragma unroll
      for (int r = 0; r < 4; ++r)
        myP[(rt * 16 + fg * 4 + r) * 64 + ct * 16 + fr] = f2bf(o[rt][ct][r]);
  asm volatile("s_waitcnt lgkmcnt(0)" ::: "memory");
  {
    int r_ = lane >> 1, hb = lane & 1;
    const u16* vp = vh + ((size_t)z * 1024 + row0 + r_) * 64;
    const u16* pp = P1h + ((size_t)z * 1024 + row0 + r_) * 64;
    u16* op = OH + ((size_t)b * 1024 + row0 + r_) * 1024 + h * 64;
#pragma unroll
    for (int c = 0; c < 4; ++c) {
      int ch = hb * 4 + c;
      short8 pv = *(const short8*)(myP + r_ * 64 + ch * 8);
      short8 vv = *(const short8*)(vp + ch * 8);
      short8 p1 = *(const short8*)(pp + ch * 8);
      short8 res;
#pragma unroll
      for (int e = 0; e < 8; ++e) {
        float f = cw0 * bf2f((u16)vv[e]) + cw1 * bf2f((u16)p1[e]) +
                  cw2 * bf2f((u16)pv[e]);
        res[e] = (short)f2bf(f);
      }
      *(short8*)(op + ch * 8) = res;
    }
  }
}

// ------------------------------------------------- final: out = OH @ Wo + bo
__global__ __launch_bounds__(256) void k_final(const u16* __restrict__ OH,
                                               const u16* __restrict__ WoT,
                                               const float* __restrict__ bo,
                                               float* __restrict__ out) {
  __shared__ __align__(16) u16 As[3 * 128 * 32];
  __shared__ __align__(16) u16 Bs[3 * 64 * 32];
  const int li = blockIdx.x + 32 * blockIdx.y;
  const int cx = li & 7, jb = li >> 3;
  const int m0 = (cx * 4 + (jb & 3)) * 128;
  const int n0 = (jb >> 2) * 64;
  f32x4 acc[2][4];
  core128x64_p3(OH + (size_t)m0 * 1024, WoT + (size_t)n0 * 1024, 1024, acc, As, Bs);
  const int tid = threadIdx.x, lane = tid & 63, w = tid >> 6;
  const int fr = lane & 15, fg = lane >> 4;
#pragma unroll
  for (int i = 0; i < 2; ++i)
#pragma unroll
    for (int j2 = 0; j2 < 4; ++j2) {
      int n = n0 + j2 * 16 + fr;
      float bb = bo[n];
#pragma unroll
      for (int r = 0; r < 4; ++r) {
        int m = m0 + w * 32 + i * 16 + fg * 4 + r;
        out[(size_t)m * 1024 + n] = acc[i][j2][r] + bb;
      }
    }
}

extern "C" void kernel_launch(void* const* d_in, const int* in_sizes, int n_in,
                              void* d_out, int out_size, void* d_ws,
                              size_t ws_size, hipStream_t stream) {
  const float* x = (const float*)d_in[0];
  const float* Wq = (const float*)d_in[1];
  const float* bq = (const float*)d_in[2];
  const float* Wk = (const float*)d_in[3];
  const float* bk = (const float*)d_in[4];
  const float* Wv = (const float*)d_in[5];
  const float* bv = (const float*)d_in[6];
  const float* Wo = (const float*)d_in[7];
  const float* bo = (const float*)d_in[8];
  const float* w0 = (const float*)d_in[9];
  const float* w1 = (const float*)d_in[10];
  const float* wK = (const float*)d_in[11];
  float* out = (float*)d_out;

  char* ws = (char*)d_ws;
  const size_t MB = 1ull << 20;
  u16* xb  = (u16*)(ws);             // 8 MiB
  u16* WqT = (u16*)(ws + 8 * MB);    // 2 MiB
  u16* WkT = (u16*)(ws + 10 * MB);   // 2 MiB
  u16* WvT = (u16*)(ws + 12 * MB);   // 2 MiB
  u16* WoT = (u16*)(ws + 14 * MB);   // 2 MiB
  u16* qh  = (u16*)(ws + 16 * MB);   // 8 MiB  [z][n][d]
  u16* kh  = (u16*)(ws + 24 * MB);   // 8 MiB  [z][n][d]
  u16* vh  = (u16*)(ws + 32 * MB);   // 8 MiB  [z][n][d]
  u16* vT  = (u16*)(ws + 40 * MB);   // 8 MiB  [z][d][n]
  u16* P1T = (u16*)(ws + 48 * MB);   // 8 MiB  [z][d][n]
  u16* P1h = (u16*)(ws + 56 * MB);   // 8 MiB  [z][n][d]
  u16* OH  = (u16*)(ws + 64 * MB);   // 8 MiB  [b][n][D]
  float* mlinv = (float*)(ws + 72 * MB);  // 256 KiB [z][n]

  hipLaunchKernelGGL(k_cast_x, dim3(4096), dim3(256), 0, stream, x, xb);
  hipLaunchKernelGGL(k_trans_w, dim3(32, 32, 4), dim3(256), 0, stream, Wq, Wk,
                     Wv, Wo, WqT, WkT, WvT, WoT);
  hipLaunchKernelGGL(k_proj, dim3(16, 8, 3), dim3(512), 0, stream, xb, WqT, WkT,
                     WvT, bq, bk, bv, qh, kh, vh, vT);
  hipLaunchKernelGGL(k_pass1, dim3(8, 64), dim3(256), 0, stream, qh, kh, vT,
                     P1T, P1h, mlinv);
  hipLaunchKernelGGL(k_pass2, dim3(8, 64), dim3(256), 0, stream, qh, kh, P1T,
                     vh, P1h, mlinv, w0, w1, wK, OH);
  hipLaunchKernelGGL(k_final, dim3(32, 16), dim3(256), 0, stream, OH, WoT, bo,
                     out);
}

// Round 14
// 156.219 us; speedup vs baseline: 1.1961x; 1.1491x over previous
//
#include <hip/hip_runtime.h>

typedef unsigned short u16;
typedef unsigned int u32;
typedef __attribute__((ext_vector_type(8))) short short8;
typedef __attribute__((ext_vector_type(4))) float f32x4;

__device__ __forceinline__ u16 f2bf(float f) {
  union { float f; u32 u; } c; c.f = f;
  u32 u = c.u;
  u += 0x7fffu + ((u >> 16) & 1u);  // round-to-nearest-even
  return (u16)(u >> 16);
}
__device__ __forceinline__ float bf2f(u16 h) {
  union { u32 u; float f; } c; c.u = ((u32)h) << 16;
  return c.f;
}

// async global->LDS, 16B per lane; LDS dest must be linear in lane order
#define GLDS16(g, l)                                                          \
  __builtin_amdgcn_global_load_lds(                                           \
      (const __attribute__((address_space(1))) u32*)(g),                      \
      (__attribute__((address_space(3))) u32*)(l), 16, 0, 0)

// exp(x*0.125) == exp2(x * 0.125*log2(e))
#define EXP_SCALE 0.18033688011112042f

// ---------------------------------------------------------------- cast x
__global__ __launch_bounds__(256) void k_cast_x(const float* __restrict__ x,
                                                u16* __restrict__ xb) {
  int i = blockIdx.x * 256 + threadIdx.x;
  float4 v = ((const float4*)x)[i];
  short4 s;
  s.x = (short)f2bf(v.x); s.y = (short)f2bf(v.y);
  s.z = (short)f2bf(v.z); s.w = (short)f2bf(v.w);
  *(short4*)(xb + (size_t)i * 4) = s;
}

// ------------------------------------------- transpose + cast weights (D=1024)
__global__ __launch_bounds__(256) void k_trans_w(
    const float* __restrict__ W0, const float* __restrict__ W1,
    const float* __restrict__ W2, const float* __restrict__ W3,
    u16* __restrict__ T0, u16* __restrict__ T1, u16* __restrict__ T2,
    u16* __restrict__ T3) {
  const float* W = blockIdx.z == 0 ? W0 : blockIdx.z == 1 ? W1 : blockIdx.z == 2 ? W2 : W3;
  u16* T = blockIdx.z == 0 ? T0 : blockIdx.z == 1 ? T1 : blockIdx.z == 2 ? T2 : T3;
  __shared__ float tile[32][33];
  int r0 = blockIdx.y * 32, c0 = blockIdx.x * 32;
  int tid = threadIdx.x;
  for (int i = tid; i < 1024; i += 256) {
    int r = i >> 5, c = i & 31;
    tile[r][c] = W[(size_t)(r0 + r) * 1024 + c0 + c];
  }
  __syncthreads();
  for (int i = tid; i < 1024; i += 256) {
    int r = i >> 5, c = i & 31;
    T[(size_t)(c0 + r) * 1024 + r0 + c] = f2bf(tile[c][r]);
  }
}

// ------------------------------------------------- pipelined GEMM cores (T3/T4)
// 3-slot rotation, one barrier per K-step, counted vmcnt. RACE FIX (R7):
// lgkmcnt(0) drained in the SAME waitcnt as vmcnt before every barrier --
// s_barrier does NOT drain lgkm; a straggler ds_read of the recycled slot
// must complete before other waves' global_load_lds overwrite it (WAR).
__device__ __forceinline__ void core128x128_p3(const u16* __restrict__ A,
                                               const u16* __restrict__ Bt, int K,
                                               f32x4 (&acc)[4][4], u16* As,
                                               u16* Bs) {
  const int tid = threadIdx.x;
  const int lane = tid & 63;
  const int wm = tid >> 7, wn = (tid >> 6) & 1;
  const int fr = lane & 15, fg = lane >> 4;
  const int sr = tid >> 2, sc = (tid & 3) * 8;  // staging row (0..63) / chunk
#pragma unroll
  for (int i = 0; i < 4; ++i)
#pragma unroll
    for (int j = 0; j < 4; ++j) acc[i][j] = f32x4{0.f, 0.f, 0.f, 0.f};

  auto stage = [&](int t, int slot) {
    u16* as = As + slot * 4096;
    u16* bs = Bs + slot * 4096;
    const int k0 = t * 32 + sc;
    GLDS16(A + (size_t)sr * K + k0, as + tid * 8);
    GLDS16(A + (size_t)(sr + 64) * K + k0, as + (256 + tid) * 8);
    GLDS16(Bt + (size_t)sr * K + k0, bs + tid * 8);
    GLDS16(Bt + (size_t)(sr + 64) * K + k0, bs + (256 + tid) * 8);
  };
  auto compute = [&](int slot) {
    const u16* as = As + slot * 4096;
    const u16* bs = Bs + slot * 4096;
    short8 af[4], bfv[4];
#pragma unroll
    for (int i = 0; i < 4; ++i)
      af[i] = *(const short8*)(as + (wm * 64 + i * 16 + fr) * 32 + fg * 8);
#pragma unroll
    for (int j = 0; j < 4; ++j)
      bfv[j] = *(const short8*)(bs + (wn * 64 + j * 16 + fr) * 32 + fg * 8);
#pragma unroll
    for (int i = 0; i < 4; ++i)
#pragma unroll
      for (int j = 0; j < 4; ++j)
        acc[i][j] = __builtin_amdgcn_mfma_f32_16x16x32_bf16(af[i], bfv[j],
                                                            acc[i][j], 0, 0, 0);
  };

  const int NS = K / 32;
  stage(0, 0);
  stage(1, 1);
  int cs = 0, ss = 2;
  for (int t = 0; t + 2 < NS; ++t) {
    asm volatile("s_waitcnt vmcnt(4) lgkmcnt(0)" ::: "memory");
    __builtin_amdgcn_s_barrier();
    asm volatile("" ::: "memory");
    stage(t + 2, ss);
    compute(cs);
    cs = cs == 2 ? 0 : cs + 1;
    ss = ss == 2 ? 0 : ss + 1;
  }
  asm volatile("s_waitcnt vmcnt(4) lgkmcnt(0)" ::: "memory");
  __builtin_amdgcn_s_barrier();
  asm volatile("" ::: "memory");
  compute(cs);
  cs = cs == 2 ? 0 : cs + 1;
  asm volatile("s_waitcnt vmcnt(0) lgkmcnt(0)" ::: "memory");
  __builtin_amdgcn_s_barrier();
  asm volatile("" ::: "memory");
  compute(cs);
}

__device__ __forceinline__ void core128x64_p3(const u16* __restrict__ A,
                                              const u16* __restrict__ Bt, int K,
                                              f32x4 (&acc)[2][4], u16* As,
                                              u16* Bs) {
  const int tid = threadIdx.x;
  const int lane = tid & 63;
  const int w = tid >> 6;
  const int fr = lane & 15, fg = lane >> 4;
  const int sr = tid >> 2, sc = (tid & 3) * 8;
#pragma unroll
  for (int i = 0; i < 2; ++i)
#pragma unroll
    for (int j = 0; j < 4; ++j) acc[i][j] = f32x4{0.f, 0.f, 0.f, 0.f};

  auto stage = [&](int t, int slot) {
    u16* as = As + slot * 4096;
    u16* bs = Bs + slot * 2048;
    const int k0 = t * 32 + sc;
    GLDS16(A + (size_t)sr * K + k0, as + tid * 8);
    GLDS16(A + (size_t)(sr + 64) * K + k0, as + (256 + tid) * 8);
    GLDS16(Bt + (size_t)sr * K + k0, bs + tid * 8);
  };
  auto compute = [&](int slot) {
    const u16* as = As + slot * 4096;
    const u16* bs = Bs + slot * 2048;
    short8 af[2], bfv[4];
#pragma unroll
    for (int i = 0; i < 2; ++i)
      af[i] = *(const short8*)(as + (w * 32 + i * 16 + fr) * 32 + fg * 8);
#pragma unroll
    for (int j = 0; j < 4; ++j)
      bfv[j] = *(const short8*)(bs + (j * 16 + fr) * 32 + fg * 8);
#pragma unroll
    for (int i = 0; i < 2; ++i)
#pragma unroll
      for (int j = 0; j < 4; ++j)
        acc[i][j] = __builtin_amdgcn_mfma_f32_16x16x32_bf16(af[i], bfv[j],
                                                            acc[i][j], 0, 0, 0);
  };

  const int NS = K / 32;
  stage(0, 0);
  stage(1, 1);
  int cs = 0, ss = 2;
  for (int t = 0; t + 2 < NS; ++t) {
    asm volatile("s_waitcnt vmcnt(3) lgkmcnt(0)" ::: "memory");
    __builtin_amdgcn_s_barrier();
    asm volatile("" ::: "memory");
    stage(t + 2, ss);
    compute(cs);
    cs = cs == 2 ? 0 : cs + 1;
    ss = ss == 2 ? 0 : ss + 1;
  }
  asm volatile("s_waitcnt vmcnt(3) lgkmcnt(0)" ::: "memory");
  __builtin_amdgcn_s_barrier();
  asm volatile("" ::: "memory");
  compute(cs);
  cs = cs == 2 ? 0 : cs + 1;
  asm volatile("s_waitcnt vmcnt(0) lgkmcnt(0)" ::: "memory");
  __builtin_amdgcn_s_barrier();
  asm volatile("" ::: "memory");
  compute(cs);
}

// ------------------------------------------------------- fused QKV projection
// R14: reverted to the R8 global-best config (128^2, 3-slot, 12 waves/CU --
// sits on the measured ~0.55 TB/s-per-wave issue ceiling; all larger-tile /
// deeper-pipeline variants measured slower).
__global__ __launch_bounds__(256) void k_proj(
    const u16* __restrict__ xb, const u16* __restrict__ WqT,
    const u16* __restrict__ WkT, const u16* __restrict__ WvT,
    const float* __restrict__ bq, const float* __restrict__ bk,
    const float* __restrict__ bv, u16* __restrict__ qh, u16* __restrict__ kh,
    u16* __restrict__ vh, u16* __restrict__ vT) {
  __shared__ __align__(16) u16 As[3 * 128 * 32];
  __shared__ __align__(16) u16 Bs[3 * 128 * 32];
  const int li = blockIdx.x + 32 * (blockIdx.y + 8 * blockIdx.z);
  const int cx = li & 7, jb = li >> 3;
  const int m0 = (cx * 4 + (jb & 3)) * 128;
  const int n0 = ((jb >> 2) & 7) * 128;
  const int which = jb >> 5;
  const u16* Bt = which == 0 ? WqT : which == 1 ? WkT : WvT;
  const float* bias = which == 0 ? bq : which == 1 ? bk : bv;
  f32x4 acc[4][4];
  core128x128_p3(xb + (size_t)m0 * 1024, Bt + (size_t)n0 * 1024, 1024, acc, As, Bs);
  const int tid = threadIdx.x, lane = tid & 63;
  const int wm = tid >> 7, wn = (tid >> 6) & 1, fr = lane & 15, fg = lane >> 4;
#pragma unroll
  for (int i = 0; i < 4; ++i)
#pragma unroll
    for (int j2 = 0; j2 < 4; ++j2) {
      int n = n0 + wn * 64 + j2 * 16 + fr;
      float bb = bias[n];
      int h = n >> 6, dc = n & 63;
#pragma unroll
      for (int r = 0; r < 4; ++r) {
        int m = m0 + wm * 64 + i * 16 + fg * 4 + r;
        int b = m >> 10, nr = m & 1023;
        int z = b * 16 + h;
        float val = acc[i][j2][r] + bb;
        u16 bv16 = f2bf(val);
        if (which == 0) {
          qh[((size_t)z * 1024 + nr) * 64 + dc] = bv16;
        } else if (which == 1) {
          kh[((size_t)z * 1024 + nr) * 64 + dc] = bv16;
        } else {
          vh[((size_t)z * 1024 + nr) * 64 + dc] = bv16;
          vT[((size_t)z * 64 + dc) * 1024 + nr] = bv16;
        }
      }
    }
}

// -------------------------------------------------------------- pass 1
// QBLK=64 (4 waves x 16 rows), no-max softmax (data-safe: |S/8|<~6),
// deferred sum-reduce. L2-resident K/V per z; 1024 blocks keep ~16 waves/CU.
__global__ __launch_bounds__(256) void k_pass1(
    const u16* __restrict__ qh, const u16* __restrict__ kh,
    const u16* __restrict__ vT, u16* __restrict__ P1T,
    u16* __restrict__ P1h, float* __restrict__ mlinv) {
  __shared__ __align__(16) u16 Ks[64 * 64];
  __shared__ __align__(16) u16 Vs[64 * 64];
  __shared__ __align__(16) u16 Ps[4][16 * 64];
  const int li = blockIdx.x + 16 * blockIdx.y;
  const int cx = li & 7, jb = li >> 3;
  const int z = cx * 8 + (jb >> 4);
  const int m0 = (jb & 15) * 64;
  const int tid = threadIdx.x, lane = tid & 63, w = tid >> 6;
  const int fr = lane & 15, fg = lane >> 4;
  const int row0 = m0 + w * 16;
  const u16* qbase = qh + (size_t)z * 65536;
  const u16* kbase = kh + (size_t)z * 65536;
  const u16* vbase = vT + (size_t)z * 65536;
  u16* myP = &Ps[w][0];

  short8 qf[2];
#pragma unroll
  for (int kc = 0; kc < 2; ++kc)
    qf[kc] = *(const short8*)(qbase + (size_t)(row0 + fr) * 64 + (kc * 4 + fg) * 8);

  f32x4 o[4];
  float rs[4];
#pragma unroll
  for (int ct = 0; ct < 4; ++ct) o[ct] = f32x4{0.f, 0.f, 0.f, 0.f};
#pragma unroll
  for (int r = 0; r < 4; ++r) rs[r] = 0.f;

  for (int t = 0; t < 16; ++t) {
    const int kv0 = t * 64;
#pragma unroll
    for (int it = 0; it < 2; ++it) {
      int idx = it * 256 + tid;
      int row = idx >> 3, cc = idx & 7;
      GLDS16(kbase + (size_t)(kv0 + row) * 64 + ((cc ^ (row & 7)) * 8),
             Ks + idx * 8);
      GLDS16(vbase + (size_t)row * 1024 + kv0 + ((cc ^ (row & 7)) * 8),
             Vs + idx * 8);
    }
    __syncthreads();
    // S = q @ k^T ; P = exp2(S*c) ; accumulate per-lane partial row-sums
#pragma unroll
    for (int ct = 0; ct < 4; ++ct) {
      int krow = ct * 16 + fr;
      short8 k0 = *(const short8*)(Ks + krow * 64 + ((fg ^ (krow & 7)) * 8));
      short8 k1 = *(const short8*)(Ks + krow * 64 + (((4 + fg) ^ (krow & 7)) * 8));
      f32x4 s = __builtin_amdgcn_mfma_f32_16x16x32_bf16(
          qf[0], k0, f32x4{0.f, 0.f, 0.f, 0.f}, 0, 0, 0);
      s = __builtin_amdgcn_mfma_f32_16x16x32_bf16(qf[1], k1, s, 0, 0, 0);
      int pcol = ct * 16 + fr;
      int cc = pcol >> 3;
#pragma unroll
      for (int r = 0; r < 4; ++r) {
        float e = __builtin_exp2f(s[r] * EXP_SCALE);
        rs[r] += e;
        int prow = fg * 4 + r;
        myP[prow * 64 + ((cc ^ (prow & 7)) * 8) + (pcol & 7)] = f2bf(e);
      }
    }
    asm volatile("s_waitcnt lgkmcnt(0)" ::: "memory");
    // ---- O += P @ V ----
    short8 p0 = *(const short8*)(myP + fr * 64 + ((fg ^ (fr & 7)) * 8));
    short8 p1 = *(const short8*)(myP + fr * 64 + (((4 + fg) ^ (fr & 7)) * 8));
#pragma unroll
    for (int ct = 0; ct < 4; ++ct) {
      int vrow = ct * 16 + fr;
      short8 v0 = *(const short8*)(Vs + vrow * 64 + ((fg ^ (vrow & 7)) * 8));
      short8 v1 = *(const short8*)(Vs + vrow * 64 + (((4 + fg) ^ (vrow & 7)) * 8));
      o[ct] = __builtin_amdgcn_mfma_f32_16x16x32_bf16(p0, v0, o[ct], 0, 0, 0);
      o[ct] = __builtin_amdgcn_mfma_f32_16x16x32_bf16(p1, v1, o[ct], 0, 0, 0);
    }
    __syncthreads();
  }
  // ---- deferred row-sum reduce over the 16 fr lanes ----
#pragma unroll
  for (int off = 1; off < 16; off <<= 1)
#pragma unroll
    for (int r = 0; r < 4; ++r) rs[r] += __shfl_xor(rs[r], off, 64);
  float linv[4];
#pragma unroll
  for (int r = 0; r < 4; ++r) linv[r] = 1.f / rs[r];
  // ---- epilogue: normalize, write P1T + P1h + stats ----
#pragma unroll
  for (int ct = 0; ct < 4; ++ct) {
    union { u16 u[4]; short4 s4; } pk;
#pragma unroll
    for (int r = 0; r < 4; ++r) {
      u16 b_ = f2bf(o[ct][r] * linv[r]);
      pk.u[r] = b_;
      myP[(fg * 4 + r) * 64 + ct * 16 + fr] = b_;  // linear stage
    }
    *(short4*)(P1T + ((size_t)z * 64 + ct * 16 + fr) * 1024 + row0 + fg * 4) =
        pk.s4;
  }
  asm volatile("s_waitcnt lgkmcnt(0)" ::: "memory");
  {
    int r_ = lane >> 2;
#pragma unroll
    for (int ch2 = 0; ch2 < 2; ++ch2) {
      int ch = (lane & 3) * 2 + ch2;
      int4 vv = *(const int4*)(myP + r_ * 64 + ch * 8);
      *(int4*)(P1h + ((size_t)z * 1024 + row0 + r_) * 64 + ch * 8) = vv;
    }
  }
  if (fr == 0) {
#pragma unroll
    for (int r = 0; r < 4; ++r)
      mlinv[(size_t)z * 1024 + row0 + fg * 4 + r] = linv[r];
  }
}

// -------------------------------------------------------------- pass 2
// Recompute S (same frags/order), P = exp2(S*c)*linv, O2 += P@P1; fused
// epilogue OH = cw0*v + cw1*P1 + cw2*O2, coalesced.
__global__ __launch_bounds__(256) void k_pass2(
    const u16* __restrict__ qh, const u16* __restrict__ kh,
    const u16* __restrict__ P1T, const u16* __restrict__ vh,
    const u16* __restrict__ P1h, const float* __restrict__ mlinv,
    const float* __restrict__ w0, const float* __restrict__ w1,
    const float* __restrict__ wK, u16* __restrict__ OH) {
  __shared__ __align__(16) u16 Ks[64 * 64];
  __shared__ __align__(16) u16 Ts[64 * 64];
  __shared__ __align__(16) u16 Ps[4][16 * 64];
  const int li = blockIdx.x + 16 * blockIdx.y;
  const int cx = li & 7, jb = li >> 3;
  const int z = cx * 8 + (jb >> 4);
  const int m0 = (jb & 15) * 64;
  const int tid = threadIdx.x, lane = tid & 63, w = tid >> 6;
  const int fr = lane & 15, fg = lane >> 4;
  const int row0 = m0 + w * 16;
  const int h = z & 15, b = z >> 4;
  const float cw0 = w0[h], cw1 = w1[h] - wK[h], cw2 = 2.f * wK[h];
  const u16* qbase = qh + (size_t)z * 65536;
  const u16* kbase = kh + (size_t)z * 65536;
  const u16* tbase = P1T + (size_t)z * 65536;
  u16* myP = &Ps[w][0];

  short8 qf[2];
#pragma unroll
  for (int kc = 0; kc < 2; ++kc)
    qf[kc] = *(const short8*)(qbase + (size_t)(row0 + fr) * 64 + (kc * 4 + fg) * 8);
  float lrow[4];
#pragma unroll
  for (int r = 0; r < 4; ++r)
    lrow[r] = mlinv[(size_t)z * 1024 + row0 + fg * 4 + r];
  f32x4 o[4];
#pragma unroll
  for (int ct = 0; ct < 4; ++ct) o[ct] = f32x4{0.f, 0.f, 0.f, 0.f};

  for (int t = 0; t < 16; ++t) {
    const int kv0 = t * 64;
#pragma unroll
    for (int it = 0; it < 2; ++it) {
      int idx = it * 256 + tid;
      int row = idx >> 3, cc = idx & 7;
      GLDS16(kbase + (size_t)(kv0 + row) * 64 + ((cc ^ (row & 7)) * 8),
             Ks + idx * 8);
      GLDS16(tbase + (size_t)row * 1024 + kv0 + ((cc ^ (row & 7)) * 8),
             Ts + idx * 8);
    }
    __syncthreads();
#pragma unroll
    for (int ct = 0; ct < 4; ++ct) {
      int krow = ct * 16 + fr;
      short8 k0 = *(const short8*)(Ks + krow * 64 + ((fg ^ (krow & 7)) * 8));
      short8 k1 = *(const short8*)(Ks + krow * 64 + (((4 + fg) ^ (krow & 7)) * 8));
      f32x4 s = __builtin_amdgcn_mfma_f32_16x16x32_bf16(
          qf[0], k0, f32x4{0.f, 0.f, 0.f, 0.f}, 0, 0, 0);
      s = __builtin_amdgcn_mfma_f32_16x16x32_bf16(qf[1], k1, s, 0, 0, 0);
      int pcol = ct * 16 + fr;
      int cc = pcol >> 3;
#pragma unroll
      for (int r = 0; r < 4; ++r) {
        float p = __builtin_exp2f(s[r] * EXP_SCALE) * lrow[r];
        int prow = fg * 4 + r;
        myP[prow * 64 + ((cc ^ (prow & 7)) * 8) + (pcol & 7)] = f2bf(p);
      }
    }
    asm volatile("s_waitcnt lgkmcnt(0)" ::: "memory");
    short8 p0 = *(const short8*)(myP + fr * 64 + ((fg ^ (fr & 7)) * 8));
    short8 p1 = *(const short8*)(myP + fr * 64 + (((4 + fg) ^ (fr & 7)) * 8));
#pragma unroll
    for (int ct = 0; ct < 4; ++ct) {
      int vrow = ct * 16 + fr;
      short8 v0 = *(const short8*)(Ts + vrow * 64 + ((fg ^ (vrow & 7)) * 8));
      short8 v1 = *(const short8*)(Ts + vrow * 64 + (((4 + fg) ^ (vrow & 7)) * 8));
      o[ct] = __builtin_amdgcn_mfma_f32_16x16x32_bf16(p0, v0, o[ct], 0, 0, 0);
      o[ct] = __builtin_amdgcn_mfma_f32_16x16x32_bf16(p1, v1, o[ct], 0, 0, 0);
    }
    __syncthreads();
  }
  // ---- epilogue: OH = cw0*v + cw1*P1 + cw2*O2, coalesced via LDS stage ----
#pragma unroll
  for (int ct = 0; ct < 4; ++ct)
#pragma unroll
    for (int r = 0; r < 4; ++r)
      myP[(fg * 4 + r) * 64 + ct * 16 + fr] = f2bf(o[ct][r]);
  asm volatile("s_waitcnt lgkmcnt(0)" ::: "memory");
  {
    int r_ = lane >> 2;
    const u16* vp = vh + ((size_t)z * 1024 + row0 + r_) * 64;
    const u16* pp = P1h + ((size_t)z * 1024 + row0 + r_) * 64;
    u16* op = OH + ((size_t)b * 1024 + row0 + r_) * 1024 + h * 64;
#pragma unroll
    for (int ch2 = 0; ch2 < 2; ++ch2) {
      int ch = (lane & 3) * 2 + ch2;
      short8 pv = *(const short8*)(myP + r_ * 64 + ch * 8);
      short8 vv = *(const short8*)(vp + ch * 8);
      short8 p1 = *(const short8*)(pp + ch * 8);
      short8 res;
#pragma unroll
      for (int e = 0; e < 8; ++e) {
        float f = cw0 * bf2f((u16)vv[e]) + cw1 * bf2f((u16)p1[e]) +
                  cw2 * bf2f((u16)pv[e]);
        res[e] = (short)f2bf(f);
      }
      *(short8*)(op + ch * 8) = res;
    }
  }
}

// ------------------------------------------------- final: out = OH @ Wo + bo
__global__ __launch_bounds__(256) void k_final(const u16* __restrict__ OH,
                                               const u16* __restrict__ WoT,
                                               const float* __restrict__ bo,
                                               float* __restrict__ out) {
  __shared__ __align__(16) u16 As[3 * 128 * 32];
  __shared__ __align__(16) u16 Bs[3 * 64 * 32];
  const int li = blockIdx.x + 32 * blockIdx.y;
  const int cx = li & 7, jb = li >> 3;
  const int m0 = (cx * 4 + (jb & 3)) * 128;
  const int n0 = (jb >> 2) * 64;
  f32x4 acc[2][4];
  core128x64_p3(OH + (size_t)m0 * 1024, WoT + (size_t)n0 * 1024, 1024, acc, As, Bs);
  const int tid = threadIdx.x, lane = tid & 63, w = tid >> 6;
  const int fr = lane & 15, fg = lane >> 4;
#pragma unroll
  for (int i = 0; i < 2; ++i)
#pragma unroll
    for (int j2 = 0; j2 < 4; ++j2) {
      int n = n0 + j2 * 16 + fr;
      float bb = bo[n];
#pragma unroll
      for (int r = 0; r < 4; ++r) {
        int m = m0 + w * 32 + i * 16 + fg * 4 + r;
        out[(size_t)m * 1024 + n] = acc[i][j2][r] + bb;
      }
    }
}

extern "C" void kernel_launch(void* const* d_in, const int* in_sizes, int n_in,
                              void* d_out, int out_size, void* d_ws,
                              size_t ws_size, hipStream_t stream) {
  const float* x = (const float*)d_in[0];
  const float* Wq = (const float*)d_in[1];
  const float* bq = (const float*)d_in[2];
  const float* Wk = (const float*)d_in[3];
  const float* bk = (const float*)d_in[4];
  const float* Wv = (const float*)d_in[5];
  const float* bv = (const float*)d_in[6];
  const float* Wo = (const float*)d_in[7];
  const float* bo = (const float*)d_in[8];
  const float* w0 = (const float*)d_in[9];
  const float* w1 = (const float*)d_in[10];
  const float* wK = (const float*)d_in[11];
  float* out = (float*)d_out;

  char* ws = (char*)d_ws;
  const size_t MB = 1ull << 20;
  u16* xb  = (u16*)(ws);             // 8 MiB
  u16* WqT = (u16*)(ws + 8 * MB);    // 2 MiB
  u16* WkT = (u16*)(ws + 10 * MB);   // 2 MiB
  u16* WvT = (u16*)(ws + 12 * MB);   // 2 MiB
  u16* WoT = (u16*)(ws + 14 * MB);   // 2 MiB
  u16* qh  = (u16*)(ws + 16 * MB);   // 8 MiB  [z][n][d]
  u16* kh  = (u16*)(ws + 24 * MB);   // 8 MiB  [z][n][d]
  u16* vh  = (u16*)(ws + 32 * MB);   // 8 MiB  [z][n][d]
  u16* vT  = (u16*)(ws + 40 * MB);   // 8 MiB  [z][d][n]
  u16* P1T = (u16*)(ws + 48 * MB);   // 8 MiB  [z][d][n]
  u16* P1h = (u16*)(ws + 56 * MB);   // 8 MiB  [z][n][d]
  u16* OH  = (u16*)(ws + 64 * MB);   // 8 MiB  [b][n][D]
  float* mlinv = (float*)(ws + 72 * MB);  // 256 KiB [z][n]

  hipLaunchKernelGGL(k_cast_x, dim3(4096), dim3(256), 0, stream, x, xb);
  hipLaunchKernelGGL(k_trans_w, dim3(32, 32, 4), dim3(256), 0, stream, Wq, Wk,
                     Wv, Wo, WqT, WkT, WvT, WoT);
  hipLaunchKernelGGL(k_proj, dim3(32, 8, 3), dim3(256), 0, stream, xb, WqT, WkT,
                     WvT, bq, bk, bv, qh, kh, vh, vT);
  hipLaunchKernelGGL(k_pass1, dim3(16, 64), dim3(256), 0, stream, qh, kh, vT,
                     P1T, P1h, mlinv);
  hipLaunchKernelGGL(k_pass2, dim3(16, 64), dim3(256), 0, stream, qh, kh, P1T,
                     vh, P1h, mlinv, w0, w1, wK, OH);
  hipLaunchKernelGGL(k_final, dim3(32, 16), dim3(256), 0, stream, OH, WoT, bo,
                     out);
}